// Round 3
// baseline (1204.775 us; speedup 1.0000x reference)
//
#include <hip/hip_runtime.h>

#define DIM 64
#define SCAN_B 256
#define BKT_SHIFT 7          // 128 nodes per bucket
#define BKT_G 128

// ---------------- bf16x2 helpers (pack with round-to-nearest-even) ---------
__device__ inline float blo(unsigned p) { return __uint_as_float(p << 16); }
__device__ inline float bhi(unsigned p) { return __uint_as_float(p & 0xffff0000u); }
__device__ inline unsigned bpack(float x, float y) {
    unsigned ux = __float_as_uint(x);
    unsigned uy = __float_as_uint(y);
    ux += 0x7fffu + ((ux >> 16) & 1u);
    uy += 0x7fffu + ((uy >> 16) & 1u);
    return (ux >> 16) | (uy & 0xffff0000u);
}

// ---------------------------------------------------------------------------
__global__ void count_deg_kernel(const int* __restrict__ adj, int total,
                                 int* __restrict__ deg) {
    int i = blockIdx.x * blockDim.x + threadIdx.x;
    if (i < total) atomicAdd(&deg[adj[i]], 1);
}

__global__ void dinv_kernel(const int* __restrict__ deg,
                            float* __restrict__ dinv, int n) {
    int i = blockIdx.x * blockDim.x + threadIdx.x;
    if (i < n) {
        int d = deg[i];
        dinv[i] = (d > 0) ? rsqrtf((float)d) : 0.0f;
    }
}

// --------------------------- prefix scan (3 stages) ------------------------
__global__ void scan_block_kernel(const int* __restrict__ deg, int n,
                                  int* __restrict__ row_ptr,
                                  int* __restrict__ blocksums) {
    __shared__ int tmp[SCAN_B];
    int i = blockIdx.x * SCAN_B + threadIdx.x;
    int v = (i < n) ? deg[i] : 0;
    tmp[threadIdx.x] = v;
    __syncthreads();
    for (int off = 1; off < SCAN_B; off <<= 1) {
        int t = (threadIdx.x >= off) ? tmp[threadIdx.x - off] : 0;
        __syncthreads();
        tmp[threadIdx.x] += t;
        __syncthreads();
    }
    if (i < n) row_ptr[i] = tmp[threadIdx.x] - v;       // exclusive
    if (threadIdx.x == SCAN_B - 1) blocksums[blockIdx.x] = tmp[SCAN_B - 1];
}

__global__ void scan_sums_kernel(int* __restrict__ blocksums, int nb) {
    __shared__ int tmp[512];
    int v = (threadIdx.x < nb) ? blocksums[threadIdx.x] : 0;
    tmp[threadIdx.x] = v;
    __syncthreads();
    for (int off = 1; off < 512; off <<= 1) {
        int t = (threadIdx.x >= off) ? tmp[threadIdx.x - off] : 0;
        __syncthreads();
        tmp[threadIdx.x] += t;
        __syncthreads();
    }
    if (threadIdx.x < nb) blocksums[threadIdx.x] = tmp[threadIdx.x] - v;  // exclusive
}

__global__ void scan_add_kernel(int* __restrict__ row_ptr,
                                const int* __restrict__ blocksums,
                                int n, int total_edges) {
    int i = blockIdx.x * blockDim.x + threadIdx.x;
    if (i < n) row_ptr[i] += blocksums[i / SCAN_B];
    if (i == n) row_ptr[n] = total_edges;
}

// --------------------- CSR build, pass 1: bucket the edges -----------------
// record = (dstLocal << 17) | src   (src < 2^17, dstLocal < 128)
// Bucket tails are only ~782 active cache lines -> writes coalesce into full
// lines (vs 16x amplification of a direct node-level scatter).
__global__ void bucket_pass1_kernel(const int* __restrict__ adj, int E,
                                    const int* __restrict__ row_ptr,
                                    int* __restrict__ pcur,
                                    unsigned* __restrict__ pairs) {
    int e = blockIdx.x * blockDim.x + threadIdx.x;
    if (e >= E) return;
    int a = adj[e];
    int b = adj[E + e];
    int kb = b >> BKT_SHIFT;
    int sb = row_ptr[kb << BKT_SHIFT] + atomicAdd(&pcur[kb], 1);
    pairs[sb] = ((unsigned)(b & (BKT_G - 1)) << 17) | (unsigned)a;
    int ka = a >> BKT_SHIFT;
    int sa = row_ptr[ka << BKT_SHIFT] + atomicAdd(&pcur[ka], 1);
    pairs[sa] = ((unsigned)(a & (BKT_G - 1)) << 17) | (unsigned)b;
}

// --------------------- CSR build, pass 2: within-bucket scatter ------------
// One workgroup per bucket; LDS cursors; csr writes confined to the bucket's
// ~16KB window -> L2-resident, full-line evictions.
__global__ void bucket_pass2_kernel(const int* __restrict__ row_ptr,
                                    const unsigned* __restrict__ pairs,
                                    int* __restrict__ csr_src, int N) {
    __shared__ int cur[BKT_G];
    int b = blockIdx.x;
    int base = b << BKT_SHIFT;
    if (threadIdx.x < BKT_G) cur[threadIdx.x] = 0;
    __syncthreads();
    int off = row_ptr[base];
    int hi = base + BKT_G; if (hi > N) hi = N;
    int cnt = row_ptr[hi] - off;
    for (int i = threadIdx.x; i < cnt; i += blockDim.x) {
        unsigned p = pairs[off + i];
        int dl  = (int)(p >> 17);
        int src = (int)(p & 0x1ffffu);
        int pos = row_ptr[base + dl] + atomicAdd(&cur[dl], 1);
        csr_src[pos] = src;
    }
}

// ------------------------------- init: xs0 = bf16(dinv ⊙ x0) ---------------
__global__ void init_xs_kernel(const float2* __restrict__ x,
                               const float* __restrict__ dinv,
                               unsigned* __restrict__ xs0, int N) {
    int t = blockIdx.x * blockDim.x + threadIdx.x;
    int v = t >> 5, h = t & 31;
    if (v >= N) return;
    size_t idx = (size_t)v * 32 + h;
    float2 xv = x[idx];
    float di = dinv[v];
    xs0[idx] = bpack(di * xv.x, di * xv.y);
}

// ------------------------------- SpMM (bf16 gather) ------------------------
// 32 threads per node, each lane owns a bf16x2 dim-pair. fp32 accumulate.
//   acc = Σ xs_in[u];  y = dinv[v]*acc;  xs_out = bf16(dinv[v]*y)
__global__ void spmm_bf16_kernel(const int* __restrict__ row_ptr,
                                 const int* __restrict__ csr_src,
                                 const float* __restrict__ dinv,
                                 const unsigned* __restrict__ xs_in,
                                 unsigned* __restrict__ xs_out, int N) {
    int t = blockIdx.x * blockDim.x + threadIdx.x;
    int v = t >> 5, h = t & 31;
    if (v >= N) return;
    int beg = row_ptr[v];
    int end = row_ptr[v + 1];
    float ax = 0.0f, ay = 0.0f;
    int j = beg;
    for (; j + 4 <= end; j += 4) {
        int s0 = csr_src[j];
        int s1 = csr_src[j + 1];
        int s2 = csr_src[j + 2];
        int s3 = csr_src[j + 3];
        unsigned p0 = xs_in[(size_t)s0 * 32 + h];
        unsigned p1 = xs_in[(size_t)s1 * 32 + h];
        unsigned p2 = xs_in[(size_t)s2 * 32 + h];
        unsigned p3 = xs_in[(size_t)s3 * 32 + h];
        ax += blo(p0) + blo(p1) + blo(p2) + blo(p3);
        ay += bhi(p0) + bhi(p1) + bhi(p2) + bhi(p3);
    }
    for (; j < end; ++j) {
        unsigned p = xs_in[(size_t)csr_src[j] * 32 + h];
        ax += blo(p);
        ay += bhi(p);
    }
    float di = dinv[v];
    float yx = di * ax, yy = di * ay;
    xs_out[(size_t)v * 32 + h] = bpack(di * yx, di * yy);
}

// ---------------- final: out = 0.25*(x0 + sqrt(d)*(xs1+xs2+xs3)) -----------
__global__ void final_kernel(const float2* __restrict__ x,
                             const int* __restrict__ deg,
                             const unsigned* __restrict__ xs1,
                             const unsigned* __restrict__ xs2,
                             const unsigned* __restrict__ xs3,
                             float2* __restrict__ out, int N) {
    int t = blockIdx.x * blockDim.x + threadIdx.x;
    int v = t >> 5, h = t & 31;
    if (v >= N) return;
    size_t idx = (size_t)v * 32 + h;
    float2 x0 = x[idx];
    float rs = sqrtf((float)deg[v]);   // deg==0 -> 0, matches xs==0
    unsigned p1 = xs1[idx], p2 = xs2[idx], p3 = xs3[idx];
    float sx = blo(p1) + blo(p2) + blo(p3);
    float sy = bhi(p1) + bhi(p2) + bhi(p3);
    float2 o;
    o.x = 0.25f * (x0.x + rs * sx);
    o.y = 0.25f * (x0.y + rs * sy);
    out[idx] = o;
}

extern "C" void kernel_launch(void* const* d_in, const int* in_sizes, int n_in,
                              void* d_out, int out_size, void* d_ws, size_t ws_size,
                              hipStream_t stream) {
    const float* x = (const float*)d_in[0];
    const int* adj = (const int*)d_in[1];
    float* out     = (float*)d_out;

    const int total_adj = in_sizes[1];   // 2*E
    const int E = total_adj / 2;
    const int N = in_sizes[0] / DIM;
    const int NB = (N + BKT_G - 1) / BKT_G;   // buckets

    // per-buffer size for csr / pairs / xs: max(2E*4, N*128), 256-aligned
    size_t BUF = (size_t)total_adj * 4;
    size_t xsb = (size_t)N * 32 * 4;
    if (xsb > BUF) BUF = xsb;
    BUF = (BUF + 255) & ~(size_t)255;

    char* ws = (char*)d_ws;
    int*      deg     = (int*)(ws);                               // 400KB
    float*    dinv    = (float*)(ws + (size_t)512 * 1024);        // 400KB
    int*      row_ptr = (int*)(ws + (size_t)1024 * 1024);         // 400KB+4
    int*      pcur    = (int*)(ws + (size_t)1536 * 1024);         // NB ints
    int*      bsums   = (int*)(ws + (size_t)1792 * 1024);         // <=512 ints
    char*     big     = ws + (size_t)2048 * 1024;
    int*      csr_src = (int*)(big);
    unsigned* xs0     = (unsigned*)(big + BUF);
    unsigned* xs1     = (unsigned*)(big + 2 * BUF);
    unsigned* xs2     = (unsigned*)(big + 3 * BUF);
    unsigned* pairs   = (unsigned*)(big + 4 * BUF);   // aliased with xs3
    unsigned* xs3     = (unsigned*)(big + 4 * BUF);   // pairs dead by layer 3

    const int B = 256;
    const int nscan = (N + SCAN_B - 1) / SCAN_B;

    // 1) degrees
    hipMemsetAsync(deg, 0, (size_t)N * sizeof(int), stream);
    count_deg_kernel<<<(total_adj + B - 1) / B, B, 0, stream>>>(adj, total_adj, deg);

    // 2) dinv
    dinv_kernel<<<(N + B - 1) / B, B, 0, stream>>>(deg, dinv, N);

    // 3) row_ptr = exclusive_scan(deg)
    scan_block_kernel<<<nscan, SCAN_B, 0, stream>>>(deg, N, row_ptr, bsums);
    scan_sums_kernel<<<1, 512, 0, stream>>>(bsums, nscan);
    scan_add_kernel<<<(N + 1 + B - 1) / B, B, 0, stream>>>(row_ptr, bsums, N, total_adj);

    // 4) CSR build: bucket pass then within-bucket scatter
    hipMemsetAsync(pcur, 0, (size_t)NB * sizeof(int), stream);
    bucket_pass1_kernel<<<(E + B - 1) / B, B, 0, stream>>>(adj, E, row_ptr, pcur, pairs);
    bucket_pass2_kernel<<<NB, B, 0, stream>>>(row_ptr, pairs, csr_src, N);

    // 5) xs0 = bf16(dinv ⊙ x0)
    const long long nthreads = (long long)N * 32;
    const int nblocks = (int)((nthreads + B - 1) / B);
    init_xs_kernel<<<nblocks, B, 0, stream>>>((const float2*)x, dinv, xs0, N);

    // 6) three propagation layers (bf16 buffers, fp32 accumulate)
    spmm_bf16_kernel<<<nblocks, B, 0, stream>>>(row_ptr, csr_src, dinv, xs0, xs1, N);
    spmm_bf16_kernel<<<nblocks, B, 0, stream>>>(row_ptr, csr_src, dinv, xs1, xs2, N);
    spmm_bf16_kernel<<<nblocks, B, 0, stream>>>(row_ptr, csr_src, dinv, xs2, xs3, N);

    // 7) out = 0.25*(x0 + sqrt(d)*(xs1+xs2+xs3))
    final_kernel<<<nblocks, B, 0, stream>>>((const float2*)x, deg, xs1, xs2, xs3,
                                            (float2*)out, N);
}

// Round 4
// 613.992 us; speedup vs baseline: 1.9622x; 1.9622x over previous
//
#include <hip/hip_runtime.h>

#define DIM 64
#define SCAN_B 256

// ---------------- bf16x2 helpers (pack with round-to-nearest-even) ---------
__device__ inline float blo(unsigned p) { return __uint_as_float(p << 16); }
__device__ inline float bhi(unsigned p) { return __uint_as_float(p & 0xffff0000u); }
__device__ inline unsigned bpack(float x, float y) {
    unsigned ux = __float_as_uint(x);
    unsigned uy = __float_as_uint(y);
    ux += 0x7fffu + ((ux >> 16) & 1u);
    uy += 0x7fffu + ((uy >> 16) & 1u);
    return (ux >> 16) | (uy & 0xffff0000u);
}

// ---------------------------------------------------------------------------
__global__ void count_deg_kernel(const int* __restrict__ adj, int total,
                                 int* __restrict__ deg) {
    int i = blockIdx.x * blockDim.x + threadIdx.x;
    if (i < total) atomicAdd(&deg[adj[i]], 1);
}

__global__ void dinv_kernel(const int* __restrict__ deg,
                            float* __restrict__ dinv, int n) {
    int i = blockIdx.x * blockDim.x + threadIdx.x;
    if (i < n) {
        int d = deg[i];
        dinv[i] = (d > 0) ? rsqrtf((float)d) : 0.0f;
    }
}

// --------------------------- prefix scan (3 stages) ------------------------
__global__ void scan_block_kernel(const int* __restrict__ deg, int n,
                                  int* __restrict__ row_ptr,
                                  int* __restrict__ blocksums) {
    __shared__ int tmp[SCAN_B];
    int i = blockIdx.x * SCAN_B + threadIdx.x;
    int v = (i < n) ? deg[i] : 0;
    tmp[threadIdx.x] = v;
    __syncthreads();
    for (int off = 1; off < SCAN_B; off <<= 1) {
        int t = (threadIdx.x >= off) ? tmp[threadIdx.x - off] : 0;
        __syncthreads();
        tmp[threadIdx.x] += t;
        __syncthreads();
    }
    if (i < n) row_ptr[i] = tmp[threadIdx.x] - v;       // exclusive
    if (threadIdx.x == SCAN_B - 1) blocksums[blockIdx.x] = tmp[SCAN_B - 1];
}

__global__ void scan_sums_kernel(int* __restrict__ blocksums, int nb) {
    __shared__ int tmp[512];
    int v = (threadIdx.x < nb) ? blocksums[threadIdx.x] : 0;
    tmp[threadIdx.x] = v;
    __syncthreads();
    for (int off = 1; off < 512; off <<= 1) {
        int t = (threadIdx.x >= off) ? tmp[threadIdx.x - off] : 0;
        __syncthreads();
        tmp[threadIdx.x] += t;
        __syncthreads();
    }
    if (threadIdx.x < nb) blocksums[threadIdx.x] = tmp[threadIdx.x] - v;  // exclusive
}

__global__ void scan_add_kernel(int* __restrict__ row_ptr,
                                const int* __restrict__ blocksums,
                                int n, int total_edges) {
    int i = blockIdx.x * blockDim.x + threadIdx.x;
    if (i < n) row_ptr[i] += blocksums[i / SCAN_B];
    if (i == n) row_ptr[n] = total_edges;
}

// ------------------------------ CSR scatter --------------------------------
// Direct per-node scatter (R2 variant, 195 us measured). 100K cursors ->
// ~32 increments each, negligible atomic contention; write amplification is
// the cost but it beats the bucketed variant's serialization by 4x.
__global__ void scatter_csr_kernel(const int* __restrict__ adj, int E,
                                   const int* __restrict__ row_ptr,
                                   int* __restrict__ cursor,
                                   int* __restrict__ csr_src) {
    int e = blockIdx.x * blockDim.x + threadIdx.x;
    if (e >= E) return;
    int a = adj[e];
    int b = adj[E + e];
    int p1 = row_ptr[b] + atomicAdd(&cursor[b], 1);
    csr_src[p1] = a;
    int p2 = row_ptr[a] + atomicAdd(&cursor[a], 1);
    csr_src[p2] = b;
}

// ------------------------------- init: xs0 = bf16(dinv ⊙ x0) ---------------
__global__ void init_xs_kernel(const float2* __restrict__ x,
                               const float* __restrict__ dinv,
                               unsigned* __restrict__ xs0, int N) {
    int t = blockIdx.x * blockDim.x + threadIdx.x;
    int v = t >> 5, h = t & 31;
    if (v >= N) return;
    size_t idx = (size_t)v * 32 + h;
    float2 xv = x[idx];
    float di = dinv[v];
    xs0[idx] = bpack(di * xv.x, di * xv.y);
}

// ------------------------------- SpMM (bf16 gather) ------------------------
// 32 threads per node, each lane owns a bf16x2 dim-pair. fp32 accumulate.
//   acc = Σ xs_in[u];  y = dinv[v]*acc;  xs_out = bf16(dinv[v]*y)
__global__ void spmm_bf16_kernel(const int* __restrict__ row_ptr,
                                 const int* __restrict__ csr_src,
                                 const float* __restrict__ dinv,
                                 const unsigned* __restrict__ xs_in,
                                 unsigned* __restrict__ xs_out, int N) {
    int t = blockIdx.x * blockDim.x + threadIdx.x;
    int v = t >> 5, h = t & 31;
    if (v >= N) return;
    int beg = row_ptr[v];
    int end = row_ptr[v + 1];
    float ax = 0.0f, ay = 0.0f;
    int j = beg;
    for (; j + 4 <= end; j += 4) {
        int s0 = csr_src[j];
        int s1 = csr_src[j + 1];
        int s2 = csr_src[j + 2];
        int s3 = csr_src[j + 3];
        unsigned p0 = xs_in[(size_t)s0 * 32 + h];
        unsigned p1 = xs_in[(size_t)s1 * 32 + h];
        unsigned p2 = xs_in[(size_t)s2 * 32 + h];
        unsigned p3 = xs_in[(size_t)s3 * 32 + h];
        ax += blo(p0) + blo(p1) + blo(p2) + blo(p3);
        ay += bhi(p0) + bhi(p1) + bhi(p2) + bhi(p3);
    }
    for (; j < end; ++j) {
        unsigned p = xs_in[(size_t)csr_src[j] * 32 + h];
        ax += blo(p);
        ay += bhi(p);
    }
    float di = dinv[v];
    float yx = di * ax, yy = di * ay;
    xs_out[(size_t)v * 32 + h] = bpack(di * yx, di * yy);
}

// ---------------- final: out = 0.25*(x0 + sqrt(d)*(xs1+xs2+xs3)) -----------
__global__ void final_kernel(const float2* __restrict__ x,
                             const int* __restrict__ deg,
                             const unsigned* __restrict__ xs1,
                             const unsigned* __restrict__ xs2,
                             const unsigned* __restrict__ xs3,
                             float2* __restrict__ out, int N) {
    int t = blockIdx.x * blockDim.x + threadIdx.x;
    int v = t >> 5, h = t & 31;
    if (v >= N) return;
    size_t idx = (size_t)v * 32 + h;
    float2 x0 = x[idx];
    float rs = sqrtf((float)deg[v]);   // deg==0 -> 0, matches xs==0
    unsigned p1 = xs1[idx], p2 = xs2[idx], p3 = xs3[idx];
    float sx = blo(p1) + blo(p2) + blo(p3);
    float sy = bhi(p1) + bhi(p2) + bhi(p3);
    float2 o;
    o.x = 0.25f * (x0.x + rs * sx);
    o.y = 0.25f * (x0.y + rs * sy);
    out[idx] = o;
}

extern "C" void kernel_launch(void* const* d_in, const int* in_sizes, int n_in,
                              void* d_out, int out_size, void* d_ws, size_t ws_size,
                              hipStream_t stream) {
    const float* x = (const float*)d_in[0];
    const int* adj = (const int*)d_in[1];
    float* out     = (float*)d_out;

    const int total_adj = in_sizes[1];   // 2*E
    const int E = total_adj / 2;
    const int N = in_sizes[0] / DIM;

    // per-buffer size for csr / xs buffers: max(2E*4, N*128), 256-aligned
    size_t BUF = (size_t)total_adj * 4;
    size_t xsb = (size_t)N * 32 * 4;
    if (xsb > BUF) BUF = xsb;
    BUF = (BUF + 255) & ~(size_t)255;

    char* ws = (char*)d_ws;
    int*      deg     = (int*)(ws);                               // 400KB
    float*    dinv    = (float*)(ws + (size_t)512 * 1024);        // 400KB
    int*      row_ptr = (int*)(ws + (size_t)1024 * 1024);         // 400KB+4
    int*      cursor  = (int*)(ws + (size_t)1536 * 1024);         // N ints
    int*      bsums   = (int*)(ws + (size_t)2048 * 1024);         // <=512 ints
    char*     big     = ws + (size_t)2304 * 1024;
    int*      csr_src = (int*)(big);
    unsigned* xs0     = (unsigned*)(big + BUF);
    unsigned* xs1     = (unsigned*)(big + 2 * BUF);
    unsigned* xs2     = (unsigned*)(big + 3 * BUF);
    unsigned* xs3     = (unsigned*)(big + 4 * BUF);

    const int B = 256;
    const int nscan = (N + SCAN_B - 1) / SCAN_B;

    // 1) degrees
    hipMemsetAsync(deg, 0, (size_t)N * sizeof(int), stream);
    count_deg_kernel<<<(total_adj + B - 1) / B, B, 0, stream>>>(adj, total_adj, deg);

    // 2) dinv
    dinv_kernel<<<(N + B - 1) / B, B, 0, stream>>>(deg, dinv, N);

    // 3) row_ptr = exclusive_scan(deg)
    scan_block_kernel<<<nscan, SCAN_B, 0, stream>>>(deg, N, row_ptr, bsums);
    scan_sums_kernel<<<1, 512, 0, stream>>>(bsums, nscan);
    scan_add_kernel<<<(N + 1 + B - 1) / B, B, 0, stream>>>(row_ptr, bsums, N, total_adj);

    // 4) CSR scatter (direct per-node cursors)
    hipMemsetAsync(cursor, 0, (size_t)N * sizeof(int), stream);
    scatter_csr_kernel<<<(E + B - 1) / B, B, 0, stream>>>(adj, E, row_ptr, cursor, csr_src);

    // 5) xs0 = bf16(dinv ⊙ x0)
    const long long nthreads = (long long)N * 32;
    const int nblocks = (int)((nthreads + B - 1) / B);
    init_xs_kernel<<<nblocks, B, 0, stream>>>((const float2*)x, dinv, xs0, N);

    // 6) three propagation layers (bf16 buffers, fp32 accumulate)
    spmm_bf16_kernel<<<nblocks, B, 0, stream>>>(row_ptr, csr_src, dinv, xs0, xs1, N);
    spmm_bf16_kernel<<<nblocks, B, 0, stream>>>(row_ptr, csr_src, dinv, xs1, xs2, N);
    spmm_bf16_kernel<<<nblocks, B, 0, stream>>>(row_ptr, csr_src, dinv, xs2, xs3, N);

    // 7) out = 0.25*(x0 + sqrt(d)*(xs1+xs2+xs3))
    final_kernel<<<nblocks, B, 0, stream>>>((const float2*)x, deg, xs1, xs2, xs3,
                                            (float2*)out, N);
}

// Round 5
// 474.097 us; speedup vs baseline: 2.5412x; 1.2951x over previous
//
#include <hip/hip_runtime.h>

#define DIM 64
#define SCAN_B 256
#define BKT_SHIFT 7          // 128 nodes per bucket
#define BKT_G 128
#define NBLK 256             // blocks in histogram/placement passes

// ---------------- bf16x2 helpers (pack with round-to-nearest-even) ---------
__device__ inline float blo(unsigned p) { return __uint_as_float(p << 16); }
__device__ inline float bhi(unsigned p) { return __uint_as_float(p & 0xffff0000u); }
__device__ inline unsigned bpack(float x, float y) {
    unsigned ux = __float_as_uint(x);
    unsigned uy = __float_as_uint(y);
    ux += 0x7fffu + ((ux >> 16) & 1u);
    uy += 0x7fffu + ((uy >> 16) & 1u);
    return (ux >> 16) | (uy & 0xffff0000u);
}

// ---------------------------------------------------------------------------
// Pass A: per-node degree (global atomics, low contention: ~32/addr) fused
// with per-(block,bucket) LDS histogram (zero global contention).
// Edge->block mapping MUST match place_kernel (same grid-stride).
// ---------------------------------------------------------------------------
__global__ void deg_hist_kernel(const int* __restrict__ adj, int E,
                                int* __restrict__ deg,
                                int* __restrict__ hist, int NB) {
    extern __shared__ int lh[];
    for (int g = threadIdx.x; g < NB; g += blockDim.x) lh[g] = 0;
    __syncthreads();
    for (int e = blockIdx.x * blockDim.x + threadIdx.x; e < E;
         e += NBLK * blockDim.x) {
        int a = adj[e];
        int b = adj[E + e];
        atomicAdd(&deg[a], 1);
        atomicAdd(&deg[b], 1);
        atomicAdd(&lh[a >> BKT_SHIFT], 1);
        atomicAdd(&lh[b >> BKT_SHIFT], 1);
    }
    __syncthreads();
    for (int g = threadIdx.x; g < NB; g += blockDim.x)
        hist[g * NBLK + blockIdx.x] = lh[g];   // bucket-major for the scan
}

__global__ void dinv_kernel(const int* __restrict__ deg,
                            float* __restrict__ dinv, int n) {
    int i = blockIdx.x * blockDim.x + threadIdx.x;
    if (i < n) {
        int d = deg[i];
        dinv[i] = (d > 0) ? rsqrtf((float)d) : 0.0f;
    }
}

// --------------------------- prefix scan (3 stages) ------------------------
__global__ void scan_block_kernel(const int* __restrict__ src, int n,
                                  int* __restrict__ dst,
                                  int* __restrict__ blocksums) {
    __shared__ int tmp[SCAN_B];
    int i = blockIdx.x * SCAN_B + threadIdx.x;
    int v = (i < n) ? src[i] : 0;
    tmp[threadIdx.x] = v;
    __syncthreads();
    for (int off = 1; off < SCAN_B; off <<= 1) {
        int t = (threadIdx.x >= off) ? tmp[threadIdx.x - off] : 0;
        __syncthreads();
        tmp[threadIdx.x] += t;
        __syncthreads();
    }
    if (i < n) dst[i] = tmp[threadIdx.x] - v;           // exclusive
    if (threadIdx.x == SCAN_B - 1) blocksums[blockIdx.x] = tmp[SCAN_B - 1];
}

__global__ void scan_sums_kernel(int* __restrict__ blocksums, int nb) {
    __shared__ int tmp[1024];
    int v = (threadIdx.x < nb) ? blocksums[threadIdx.x] : 0;
    tmp[threadIdx.x] = v;
    __syncthreads();
    for (int off = 1; off < 1024; off <<= 1) {
        int t = (threadIdx.x >= off) ? tmp[threadIdx.x - off] : 0;
        __syncthreads();
        tmp[threadIdx.x] += t;
        __syncthreads();
    }
    if (threadIdx.x < nb) blocksums[threadIdx.x] = tmp[threadIdx.x] - v;  // exclusive
}

__global__ void scan_add_kernel(int* __restrict__ dst,
                                const int* __restrict__ blocksums,
                                int n, int total) {
    int i = blockIdx.x * blockDim.x + threadIdx.x;
    if (i < n) dst[i] += blocksums[i / SCAN_B];
    if (i == n) dst[n] = total;    // row_ptr tail / harmless pad write for hist
}

// ---------------------------------------------------------------------------
// Pass C: placement. cur[g] = scanned hist -> this block's records for bucket
// g land CONTIGUOUSLY (per-(block,bucket) ~16 records = ~1 line): write
// amplification ~2x instead of 16x, and zero global-atomic contention.
// record = (dstLocal << 17) | src   (src < 2^17, dstLocal < 128)
// ---------------------------------------------------------------------------
__global__ void place_kernel(const int* __restrict__ adj, int E,
                             const int* __restrict__ hist_s,
                             unsigned* __restrict__ pairs, int NB) {
    extern __shared__ int cur[];
    for (int g = threadIdx.x; g < NB; g += blockDim.x)
        cur[g] = hist_s[g * NBLK + blockIdx.x];
    __syncthreads();
    for (int e = blockIdx.x * blockDim.x + threadIdx.x; e < E;
         e += NBLK * blockDim.x) {
        int a = adj[e];
        int b = adj[E + e];
        int pb = atomicAdd(&cur[b >> BKT_SHIFT], 1);
        pairs[pb] = ((unsigned)(b & (BKT_G - 1)) << 17) | (unsigned)a;
        int pa = atomicAdd(&cur[a >> BKT_SHIFT], 1);
        pairs[pa] = ((unsigned)(a & (BKT_G - 1)) << 17) | (unsigned)b;
    }
}

// ------------- within-bucket scatter (R3's pass2, measured ~35us) ----------
__global__ void bucket_pass2_kernel(const int* __restrict__ row_ptr,
                                    const unsigned* __restrict__ pairs,
                                    int* __restrict__ csr_src, int N) {
    __shared__ int cur[BKT_G];
    int b = blockIdx.x;
    int base = b << BKT_SHIFT;
    if (threadIdx.x < BKT_G) cur[threadIdx.x] = 0;
    __syncthreads();
    int off = row_ptr[base];
    int hi = base + BKT_G; if (hi > N) hi = N;
    int cnt = row_ptr[hi] - off;
    for (int i = threadIdx.x; i < cnt; i += blockDim.x) {
        unsigned p = pairs[off + i];
        int dl  = (int)(p >> 17);
        int src = (int)(p & 0x1ffffu);
        int pos = row_ptr[base + dl] + atomicAdd(&cur[dl], 1);
        csr_src[pos] = src;
    }
}

// ---------------- init: xs0 = bf16(dinv ⊙ x0), row = 8 uint4 ---------------
__global__ void init_xs_kernel(const float4* __restrict__ x,
                               const float* __restrict__ dinv,
                               uint4* __restrict__ xs0, int N) {
    int t = blockIdx.x * blockDim.x + threadIdx.x;
    int v = t >> 3, sub = t & 7;
    if (v >= N) return;
    float4 xa = x[(size_t)v * 16 + sub * 2];
    float4 xb = x[(size_t)v * 16 + sub * 2 + 1];
    float di = dinv[v];
    uint4 o;
    o.x = bpack(di * xa.x, di * xa.y);
    o.y = bpack(di * xa.z, di * xa.w);
    o.z = bpack(di * xb.x, di * xb.y);
    o.w = bpack(di * xb.z, di * xb.w);
    xs0[(size_t)v * 8 + sub] = o;
}

// ------------------------------- SpMM --------------------------------------
// 32 lanes per node: 4 neighbor groups x 8 uint4-subwords. Each lane loads
// 16B (dwordx4) -> 1024B per wave per VMEM instr (4x the dword variant).
// Butterfly shfl_xor(8,16) folds the 4 neighbor groups; lanes nb==0 store.
//   acc = Σ xs_in[u];  xs_out = bf16(dinv^2 * acc)   (y recovered in final)
__global__ void spmm_bf16_kernel(const int* __restrict__ row_ptr,
                                 const int* __restrict__ csr_src,
                                 const float* __restrict__ dinv,
                                 const uint4* __restrict__ xs_in,
                                 uint4* __restrict__ xs_out, int N) {
    int t = blockIdx.x * blockDim.x + threadIdx.x;
    int v = t >> 5;
    if (v >= N) return;
    int half = threadIdx.x & 31;
    int nb = half >> 3, sub = half & 7;
    int beg = row_ptr[v];
    int end = row_ptr[v + 1];
    float a0 = 0, a1 = 0, a2 = 0, a3 = 0, a4 = 0, a5 = 0, a6 = 0, a7 = 0;
    for (int j0 = beg; j0 < end; j0 += 4) {
        int idx = j0 + nb;
        if (idx < end) {
            int s = csr_src[idx];
            uint4 p = xs_in[(size_t)s * 8 + sub];
            a0 += blo(p.x); a1 += bhi(p.x);
            a2 += blo(p.y); a3 += bhi(p.y);
            a4 += blo(p.z); a5 += bhi(p.z);
            a6 += blo(p.w); a7 += bhi(p.w);
        }
    }
    // fold the 4 neighbor groups (xor 8, 16 stays within the 32-lane half)
    a0 += __shfl_xor(a0, 8);  a0 += __shfl_xor(a0, 16);
    a1 += __shfl_xor(a1, 8);  a1 += __shfl_xor(a1, 16);
    a2 += __shfl_xor(a2, 8);  a2 += __shfl_xor(a2, 16);
    a3 += __shfl_xor(a3, 8);  a3 += __shfl_xor(a3, 16);
    a4 += __shfl_xor(a4, 8);  a4 += __shfl_xor(a4, 16);
    a5 += __shfl_xor(a5, 8);  a5 += __shfl_xor(a5, 16);
    a6 += __shfl_xor(a6, 8);  a6 += __shfl_xor(a6, 16);
    a7 += __shfl_xor(a7, 8);  a7 += __shfl_xor(a7, 16);
    if (nb == 0) {
        float di = dinv[v];
        float d2 = di * di;
        uint4 o;
        o.x = bpack(d2 * a0, d2 * a1);
        o.y = bpack(d2 * a2, d2 * a3);
        o.z = bpack(d2 * a4, d2 * a5);
        o.w = bpack(d2 * a6, d2 * a7);
        xs_out[(size_t)v * 8 + sub] = o;
    }
}

// ---------------- final: out = 0.25*(x0 + sqrt(d)*(xs1+xs2+xs3)) -----------
__global__ void final_kernel(const float4* __restrict__ x,
                             const int* __restrict__ deg,
                             const uint4* __restrict__ xs1,
                             const uint4* __restrict__ xs2,
                             const uint4* __restrict__ xs3,
                             float4* __restrict__ out, int N) {
    int t = blockIdx.x * blockDim.x + threadIdx.x;
    int v = t >> 3, sub = t & 7;
    if (v >= N) return;
    size_t idx = (size_t)v * 8 + sub;
    uint4 p1 = xs1[idx], p2 = xs2[idx], p3 = xs3[idx];
    float rs = sqrtf((float)deg[v]);   // deg==0 -> 0, matches xs==0
    float s0 = blo(p1.x) + blo(p2.x) + blo(p3.x);
    float s1 = bhi(p1.x) + bhi(p2.x) + bhi(p3.x);
    float s2 = blo(p1.y) + blo(p2.y) + blo(p3.y);
    float s3 = bhi(p1.y) + bhi(p2.y) + bhi(p3.y);
    float s4 = blo(p1.z) + blo(p2.z) + blo(p3.z);
    float s5 = bhi(p1.z) + bhi(p2.z) + bhi(p3.z);
    float s6 = blo(p1.w) + blo(p2.w) + blo(p3.w);
    float s7 = bhi(p1.w) + bhi(p2.w) + bhi(p3.w);
    float4 xa = x[(size_t)v * 16 + sub * 2];
    float4 xb = x[(size_t)v * 16 + sub * 2 + 1];
    float4 oa, ob;
    oa.x = 0.25f * (xa.x + rs * s0);
    oa.y = 0.25f * (xa.y + rs * s1);
    oa.z = 0.25f * (xa.z + rs * s2);
    oa.w = 0.25f * (xa.w + rs * s3);
    ob.x = 0.25f * (xb.x + rs * s4);
    ob.y = 0.25f * (xb.y + rs * s5);
    ob.z = 0.25f * (xb.z + rs * s6);
    ob.w = 0.25f * (xb.w + rs * s7);
    out[(size_t)v * 16 + sub * 2]     = oa;
    out[(size_t)v * 16 + sub * 2 + 1] = ob;
}

extern "C" void kernel_launch(void* const* d_in, const int* in_sizes, int n_in,
                              void* d_out, int out_size, void* d_ws, size_t ws_size,
                              hipStream_t stream) {
    const float* x = (const float*)d_in[0];
    const int* adj = (const int*)d_in[1];
    float* out     = (float*)d_out;

    const int total_adj = in_sizes[1];   // 2*E
    const int E = total_adj / 2;
    const int N = in_sizes[0] / DIM;
    const int NB = (N + BKT_G - 1) / BKT_G;   // dst buckets
    const int nhist = NB * NBLK;

    // per-buffer size for csr / pairs / xs buffers
    size_t BUF = (size_t)total_adj * 4;
    size_t xsb = (size_t)N * 32 * 4;
    if (xsb > BUF) BUF = xsb;
    BUF = (BUF + 255) & ~(size_t)255;

    char* ws = (char*)d_ws;
    int*      deg     = (int*)(ws);                               // 400KB
    float*    dinv    = (float*)(ws + (size_t)512 * 1024);        // 400KB
    int*      row_ptr = (int*)(ws + (size_t)1024 * 1024);         // 400KB+4
    int*      bsums   = (int*)(ws + (size_t)1536 * 1024);         // 1024 ints
    int*      hist    = (int*)(ws + (size_t)1600 * 1024);         // ~801KB
    int*      hist_s  = (int*)(ws + (size_t)2432 * 1024);         // ~801KB
    char*     big     = ws + (size_t)3264 * 1024;
    int*      csr_src = (int*)(big);
    unsigned* pairs   = (unsigned*)(big + BUF);   // dead after pass2
    uint4*    xs0     = (uint4*)(big + BUF);      // aliases pairs (written later)
    uint4*    xs1     = (uint4*)(big + 2 * BUF);
    uint4*    xs2     = (uint4*)(big + 3 * BUF);
    uint4*    xs3     = (uint4*)(big + 4 * BUF);

    const int B = 256;

    // 1) degrees + per-(block,bucket) histogram (fused, one adj read)
    hipMemsetAsync(deg, 0, (size_t)N * sizeof(int), stream);
    deg_hist_kernel<<<NBLK, B, NB * sizeof(int), stream>>>(adj, E, deg, hist, NB);

    // 2) dinv
    dinv_kernel<<<(N + B - 1) / B, B, 0, stream>>>(deg, dinv, N);

    // 3) row_ptr = exclusive_scan(deg)
    const int nscan = (N + SCAN_B - 1) / SCAN_B;
    scan_block_kernel<<<nscan, SCAN_B, 0, stream>>>(deg, N, row_ptr, bsums);
    scan_sums_kernel<<<1, 1024, 0, stream>>>(bsums, nscan);
    scan_add_kernel<<<(N + 1 + B - 1) / B, B, 0, stream>>>(row_ptr, bsums, N, total_adj);

    // 4) hist_s = exclusive_scan(hist)  (bucket-major: global position base)
    const int nscan2 = (nhist + SCAN_B - 1) / SCAN_B;
    scan_block_kernel<<<nscan2, SCAN_B, 0, stream>>>(hist, nhist, hist_s, bsums);
    scan_sums_kernel<<<1, 1024, 0, stream>>>(bsums, nscan2);
    scan_add_kernel<<<(nhist + 1 + B - 1) / B, B, 0, stream>>>(hist_s, bsums, nhist, total_adj);

    // 5) placement into bucket-grouped pairs, then within-bucket scatter
    place_kernel<<<NBLK, B, NB * sizeof(int), stream>>>(adj, E, hist_s, pairs, NB);
    bucket_pass2_kernel<<<NB, B, 0, stream>>>(row_ptr, pairs, csr_src, N);

    // 6) xs0 = bf16(dinv ⊙ x0)   (safe: pairs dead after pass2, same stream)
    const int nblocks8 = (int)(((long long)N * 8 + B - 1) / B);
    init_xs_kernel<<<nblocks8, B, 0, stream>>>((const float4*)x, dinv, xs0, N);

    // 7) three propagation layers (bf16 buffers, fp32 accumulate)
    const int nblocks32 = (int)(((long long)N * 32 + B - 1) / B);
    spmm_bf16_kernel<<<nblocks32, B, 0, stream>>>(row_ptr, csr_src, dinv, xs0, xs1, N);
    spmm_bf16_kernel<<<nblocks32, B, 0, stream>>>(row_ptr, csr_src, dinv, xs1, xs2, N);
    spmm_bf16_kernel<<<nblocks32, B, 0, stream>>>(row_ptr, csr_src, dinv, xs2, xs3, N);

    // 8) out = 0.25*(x0 + sqrt(d)*(xs1+xs2+xs3))
    final_kernel<<<nblocks8, B, 0, stream>>>((const float4*)x, deg, xs1, xs2, xs3,
                                             (float4*)out, N);
}

// Round 6
// 345.725 us; speedup vs baseline: 3.4848x; 1.3713x over previous
//
#include <hip/hip_runtime.h>

#define DIM 64
#define SCAN_B 256
#define BKT_SHIFT 7          // 128 nodes per bucket
#define BKT_G 128
#define NBLK 256             // blocks in histogram/placement passes
// NOTE: src packed in 17 bits -> requires N <= 131072 (N=100000 here)

// ---------------- bf16x2 helpers (pack with round-to-nearest-even) ---------
__device__ inline float blo(unsigned p) { return __uint_as_float(p << 16); }
__device__ inline float bhi(unsigned p) { return __uint_as_float(p & 0xffff0000u); }
__device__ inline unsigned bpack(float x, float y) {
    unsigned ux = __float_as_uint(x);
    unsigned uy = __float_as_uint(y);
    ux += 0x7fffu + ((ux >> 16) & 1u);
    uy += 0x7fffu + ((uy >> 16) & 1u);
    return (ux >> 16) | (uy & 0xffff0000u);
}

// ---------------------------------------------------------------------------
// Pass A: per-(block,bucket) LDS histogram ONLY — zero global atomics.
// (R5 fused global deg atomics here: 106MB of HBM write traffic, 131us.
//  Per-node degrees are now recovered inside pass2 from the bucketed pairs.)
// Edge->block mapping MUST match place_kernel (same grid-stride).
// ---------------------------------------------------------------------------
__global__ void hist_kernel(const int* __restrict__ adj, int E,
                            int* __restrict__ hist, int NB) {
    extern __shared__ int lh[];
    for (int g = threadIdx.x; g < NB; g += blockDim.x) lh[g] = 0;
    __syncthreads();
    for (int e = blockIdx.x * blockDim.x + threadIdx.x; e < E;
         e += NBLK * blockDim.x) {
        int a = adj[e];
        int b = adj[E + e];
        atomicAdd(&lh[a >> BKT_SHIFT], 1);
        atomicAdd(&lh[b >> BKT_SHIFT], 1);
    }
    __syncthreads();
    for (int g = threadIdx.x; g < NB; g += blockDim.x)
        hist[g * NBLK + blockIdx.x] = lh[g];   // bucket-major for the scan
}

// --------------------------- prefix scan (3 stages) ------------------------
__global__ void scan_block_kernel(const int* __restrict__ src, int n,
                                  int* __restrict__ dst,
                                  int* __restrict__ blocksums) {
    __shared__ int tmp[SCAN_B];
    int i = blockIdx.x * SCAN_B + threadIdx.x;
    int v = (i < n) ? src[i] : 0;
    tmp[threadIdx.x] = v;
    __syncthreads();
    for (int off = 1; off < SCAN_B; off <<= 1) {
        int t = (threadIdx.x >= off) ? tmp[threadIdx.x - off] : 0;
        __syncthreads();
        tmp[threadIdx.x] += t;
        __syncthreads();
    }
    if (i < n) dst[i] = tmp[threadIdx.x] - v;           // exclusive
    if (threadIdx.x == SCAN_B - 1) blocksums[blockIdx.x] = tmp[SCAN_B - 1];
}

__global__ void scan_sums_kernel(int* __restrict__ blocksums, int nb) {
    __shared__ int tmp[1024];
    int v = (threadIdx.x < nb) ? blocksums[threadIdx.x] : 0;
    tmp[threadIdx.x] = v;
    __syncthreads();
    for (int off = 1; off < 1024; off <<= 1) {
        int t = (threadIdx.x >= off) ? tmp[threadIdx.x - off] : 0;
        __syncthreads();
        tmp[threadIdx.x] += t;
        __syncthreads();
    }
    if (threadIdx.x < nb) blocksums[threadIdx.x] = tmp[threadIdx.x] - v;  // exclusive
}

__global__ void scan_add_kernel(int* __restrict__ dst,
                                const int* __restrict__ blocksums,
                                int n, int total) {
    int i = blockIdx.x * blockDim.x + threadIdx.x;
    if (i < n) dst[i] += blocksums[i / SCAN_B];
    if (i == n) dst[n] = total;
}

// ---------------------------------------------------------------------------
// Pass C: placement. cur[g] = scanned hist -> this block's records for bucket
// g land CONTIGUOUSLY (~2x write amplification, zero global-atomic contention).
// record = (dstLocal << 17) | src
// ---------------------------------------------------------------------------
__global__ void place_kernel(const int* __restrict__ adj, int E,
                             const int* __restrict__ hist_s,
                             unsigned* __restrict__ pairs, int NB) {
    extern __shared__ int cur[];
    for (int g = threadIdx.x; g < NB; g += blockDim.x)
        cur[g] = hist_s[g * NBLK + blockIdx.x];
    __syncthreads();
    for (int e = blockIdx.x * blockDim.x + threadIdx.x; e < E;
         e += NBLK * blockDim.x) {
        int a = adj[e];
        int b = adj[E + e];
        int pb = atomicAdd(&cur[b >> BKT_SHIFT], 1);
        pairs[pb] = ((unsigned)(b & (BKT_G - 1)) << 17) | (unsigned)a;
        int pa = atomicAdd(&cur[a >> BKT_SHIFT], 1);
        pairs[pa] = ((unsigned)(a & (BKT_G - 1)) << 17) | (unsigned)b;
    }
}

// ---------------------------------------------------------------------------
// Pass D (one block per bucket): LDS-count the bucket's 128 dstLocals ->
// deg/dinv/row_ptr as COALESCED writes (no global atomics anywhere), local
// LDS scan for row starts, then within-bucket scatter of csr_src.
// ---------------------------------------------------------------------------
__global__ void pass2_build_kernel(const unsigned* __restrict__ pairs,
                                   const int* __restrict__ hist_s,
                                   int* __restrict__ csr_src,
                                   int* __restrict__ row_ptr,
                                   int* __restrict__ deg,
                                   float* __restrict__ dinv,
                                   int N, int total_adj) {
    __shared__ int cnt[BKT_G];
    __shared__ int pre[BKT_G];
    __shared__ int cur[BKT_G];
    int g = blockIdx.x;
    int base = g << BKT_SHIFT;
    int off = hist_s[(size_t)g * NBLK];
    int offn = (g + 1 < gridDim.x) ? hist_s[(size_t)(g + 1) * NBLK] : total_adj;
    int m = offn - off;
    if (threadIdx.x < BKT_G) cnt[threadIdx.x] = 0;
    __syncthreads();
    // phase 1: count dstLocal occurrences
    for (int i = threadIdx.x; i < m; i += blockDim.x)
        atomicAdd(&cnt[pairs[off + i] >> 17], 1);
    __syncthreads();
    // phase 2: inclusive LDS scan of cnt (all threads sync, first 128 compute)
    if (threadIdx.x < BKT_G) pre[threadIdx.x] = cnt[threadIdx.x];
    __syncthreads();
    for (int o = 1; o < BKT_G; o <<= 1) {
        int t = 0;
        if (threadIdx.x < BKT_G && threadIdx.x >= o) t = pre[threadIdx.x - o];
        __syncthreads();
        if (threadIdx.x < BKT_G) pre[threadIdx.x] += t;
        __syncthreads();
    }
    // phase 3: emit deg / dinv / row_ptr (coalesced), init cursors
    if (threadIdx.x < BKT_G) {
        int v = base + threadIdx.x;
        if (v < N) {
            int c = cnt[threadIdx.x];
            int start = off + pre[threadIdx.x] - c;   // exclusive
            row_ptr[v] = start;
            deg[v] = c;
            dinv[v] = (c > 0) ? rsqrtf((float)c) : 0.0f;
            cur[threadIdx.x] = start;
        }
    }
    if (g == gridDim.x - 1 && threadIdx.x == 0) row_ptr[N] = total_adj;
    __syncthreads();
    // phase 4: scatter into csr window (L2-resident, LDS cursors)
    for (int i = threadIdx.x; i < m; i += blockDim.x) {
        unsigned p = pairs[off + i];
        int dl  = (int)(p >> 17);
        int src = (int)(p & 0x1ffffu);
        int pos = atomicAdd(&cur[dl], 1);
        csr_src[pos] = src;
    }
}

// ---------------- init: xs0 = bf16(dinv ⊙ x0), row = 8 uint4 ---------------
__global__ void init_xs_kernel(const float4* __restrict__ x,
                               const float* __restrict__ dinv,
                               uint4* __restrict__ xs0, int N) {
    int t = blockIdx.x * blockDim.x + threadIdx.x;
    int v = t >> 3, sub = t & 7;
    if (v >= N) return;
    float4 xa = x[(size_t)v * 16 + sub * 2];
    float4 xb = x[(size_t)v * 16 + sub * 2 + 1];
    float di = dinv[v];
    uint4 o;
    o.x = bpack(di * xa.x, di * xa.y);
    o.y = bpack(di * xa.z, di * xa.w);
    o.z = bpack(di * xb.x, di * xb.y);
    o.w = bpack(di * xb.z, di * xb.w);
    xs0[(size_t)v * 8 + sub] = o;
}

// ------------------------------- SpMM --------------------------------------
// 32 lanes per node: 4 neighbor groups x 8 uint4-subwords, dwordx4 gathers,
// butterfly shfl_xor(8,16) fold.  xs_out = bf16(dinv^2 * Σ xs_in[u])
__global__ void spmm_bf16_kernel(const int* __restrict__ row_ptr,
                                 const int* __restrict__ csr_src,
                                 const float* __restrict__ dinv,
                                 const uint4* __restrict__ xs_in,
                                 uint4* __restrict__ xs_out, int N) {
    int t = blockIdx.x * blockDim.x + threadIdx.x;
    int v = t >> 5;
    if (v >= N) return;
    int half = threadIdx.x & 31;
    int nb = half >> 3, sub = half & 7;
    int beg = row_ptr[v];
    int end = row_ptr[v + 1];
    float a0 = 0, a1 = 0, a2 = 0, a3 = 0, a4 = 0, a5 = 0, a6 = 0, a7 = 0;
    for (int j0 = beg; j0 < end; j0 += 4) {
        int idx = j0 + nb;
        if (idx < end) {
            int s = csr_src[idx];
            uint4 p = xs_in[(size_t)s * 8 + sub];
            a0 += blo(p.x); a1 += bhi(p.x);
            a2 += blo(p.y); a3 += bhi(p.y);
            a4 += blo(p.z); a5 += bhi(p.z);
            a6 += blo(p.w); a7 += bhi(p.w);
        }
    }
    a0 += __shfl_xor(a0, 8);  a0 += __shfl_xor(a0, 16);
    a1 += __shfl_xor(a1, 8);  a1 += __shfl_xor(a1, 16);
    a2 += __shfl_xor(a2, 8);  a2 += __shfl_xor(a2, 16);
    a3 += __shfl_xor(a3, 8);  a3 += __shfl_xor(a3, 16);
    a4 += __shfl_xor(a4, 8);  a4 += __shfl_xor(a4, 16);
    a5 += __shfl_xor(a5, 8);  a5 += __shfl_xor(a5, 16);
    a6 += __shfl_xor(a6, 8);  a6 += __shfl_xor(a6, 16);
    a7 += __shfl_xor(a7, 8);  a7 += __shfl_xor(a7, 16);
    if (nb == 0) {
        float di = dinv[v];
        float d2 = di * di;
        uint4 o;
        o.x = bpack(d2 * a0, d2 * a1);
        o.y = bpack(d2 * a2, d2 * a3);
        o.z = bpack(d2 * a4, d2 * a5);
        o.w = bpack(d2 * a6, d2 * a7);
        xs_out[(size_t)v * 8 + sub] = o;
    }
}

// ---------------- final: out = 0.25*(x0 + sqrt(d)*(xs1+xs2+xs3)) -----------
__global__ void final_kernel(const float4* __restrict__ x,
                             const int* __restrict__ deg,
                             const uint4* __restrict__ xs1,
                             const uint4* __restrict__ xs2,
                             const uint4* __restrict__ xs3,
                             float4* __restrict__ out, int N) {
    int t = blockIdx.x * blockDim.x + threadIdx.x;
    int v = t >> 3, sub = t & 7;
    if (v >= N) return;
    size_t idx = (size_t)v * 8 + sub;
    uint4 p1 = xs1[idx], p2 = xs2[idx], p3 = xs3[idx];
    float rs = sqrtf((float)deg[v]);   // deg==0 -> 0, matches xs==0
    float s0 = blo(p1.x) + blo(p2.x) + blo(p3.x);
    float s1 = bhi(p1.x) + bhi(p2.x) + bhi(p3.x);
    float s2 = blo(p1.y) + blo(p2.y) + blo(p3.y);
    float s3 = bhi(p1.y) + bhi(p2.y) + bhi(p3.y);
    float s4 = blo(p1.z) + blo(p2.z) + blo(p3.z);
    float s5 = bhi(p1.z) + bhi(p2.z) + bhi(p3.z);
    float s6 = blo(p1.w) + blo(p2.w) + blo(p3.w);
    float s7 = bhi(p1.w) + bhi(p2.w) + bhi(p3.w);
    float4 xa = x[(size_t)v * 16 + sub * 2];
    float4 xb = x[(size_t)v * 16 + sub * 2 + 1];
    float4 oa, ob;
    oa.x = 0.25f * (xa.x + rs * s0);
    oa.y = 0.25f * (xa.y + rs * s1);
    oa.z = 0.25f * (xa.z + rs * s2);
    oa.w = 0.25f * (xa.w + rs * s3);
    ob.x = 0.25f * (xb.x + rs * s4);
    ob.y = 0.25f * (xb.y + rs * s5);
    ob.z = 0.25f * (xb.z + rs * s6);
    ob.w = 0.25f * (xb.w + rs * s7);
    out[(size_t)v * 16 + sub * 2]     = oa;
    out[(size_t)v * 16 + sub * 2 + 1] = ob;
}

extern "C" void kernel_launch(void* const* d_in, const int* in_sizes, int n_in,
                              void* d_out, int out_size, void* d_ws, size_t ws_size,
                              hipStream_t stream) {
    const float* x = (const float*)d_in[0];
    const int* adj = (const int*)d_in[1];
    float* out     = (float*)d_out;

    const int total_adj = in_sizes[1];   // 2*E
    const int E = total_adj / 2;
    const int N = in_sizes[0] / DIM;
    const int NB = (N + BKT_G - 1) / BKT_G;   // dst buckets
    const int nhist = NB * NBLK;

    size_t BUF = (size_t)total_adj * 4;
    size_t xsb = (size_t)N * 32 * 4;
    if (xsb > BUF) BUF = xsb;
    BUF = (BUF + 255) & ~(size_t)255;

    char* ws = (char*)d_ws;
    int*      deg     = (int*)(ws);                               // 400KB
    float*    dinv    = (float*)(ws + (size_t)512 * 1024);        // 400KB
    int*      row_ptr = (int*)(ws + (size_t)1024 * 1024);         // 400KB+4
    int*      bsums   = (int*)(ws + (size_t)1536 * 1024);         // 1024 ints
    int*      hist    = (int*)(ws + (size_t)1600 * 1024);         // ~801KB
    int*      hist_s  = (int*)(ws + (size_t)2432 * 1024);         // ~801KB
    char*     big     = ws + (size_t)3264 * 1024;
    int*      csr_src = (int*)(big);
    unsigned* pairs   = (unsigned*)(big + BUF);   // dead after pass2
    uint4*    xs0     = (uint4*)(big + BUF);      // aliases pairs (written later)
    uint4*    xs1     = (uint4*)(big + 2 * BUF);
    uint4*    xs2     = (uint4*)(big + 3 * BUF);
    uint4*    xs3     = (uint4*)(big + 4 * BUF);

    const int B = 256;

    // 1) per-(block,bucket) histogram — no global atomics
    hist_kernel<<<NBLK, B, NB * sizeof(int), stream>>>(adj, E, hist, NB);

    // 2) hist_s = exclusive_scan(hist)  (bucket-major: global position base)
    const int nscan2 = (nhist + SCAN_B - 1) / SCAN_B;
    scan_block_kernel<<<nscan2, SCAN_B, 0, stream>>>(hist, nhist, hist_s, bsums);
    scan_sums_kernel<<<1, 1024, 0, stream>>>(bsums, nscan2);
    scan_add_kernel<<<(nhist + 1 + B - 1) / B, B, 0, stream>>>(hist_s, bsums, nhist, total_adj);

    // 3) placement into bucket-grouped pairs
    place_kernel<<<NBLK, B, NB * sizeof(int), stream>>>(adj, E, hist_s, pairs, NB);

    // 4) per-bucket: deg/dinv/row_ptr (coalesced) + csr scatter
    pass2_build_kernel<<<NB, B, 0, stream>>>(pairs, hist_s, csr_src, row_ptr,
                                             deg, dinv, N, total_adj);

    // 5) xs0 = bf16(dinv ⊙ x0)   (pairs dead after pass2, same stream)
    const int nblocks8 = (int)(((long long)N * 8 + B - 1) / B);
    init_xs_kernel<<<nblocks8, B, 0, stream>>>((const float4*)x, dinv, xs0, N);

    // 6) three propagation layers (bf16 buffers, fp32 accumulate)
    const int nblocks32 = (int)(((long long)N * 32 + B - 1) / B);
    spmm_bf16_kernel<<<nblocks32, B, 0, stream>>>(row_ptr, csr_src, dinv, xs0, xs1, N);
    spmm_bf16_kernel<<<nblocks32, B, 0, stream>>>(row_ptr, csr_src, dinv, xs1, xs2, N);
    spmm_bf16_kernel<<<nblocks32, B, 0, stream>>>(row_ptr, csr_src, dinv, xs2, xs3, N);

    // 7) out = 0.25*(x0 + sqrt(d)*(xs1+xs2+xs3))
    final_kernel<<<nblocks8, B, 0, stream>>>((const float4*)x, deg, xs1, xs2, xs3,
                                             (float4*)out, N);
}

// Round 7
// 302.159 us; speedup vs baseline: 3.9872x; 1.1442x over previous
//
#include <hip/hip_runtime.h>

#define DIM 64
#define SCAN_B 256
#define BKT_SHIFT 7          // 128 nodes per bucket
#define BKT_G 128
#define NBLK 256             // blocks in histogram/placement passes (fixed: scan layout)
#define HIST_B 1024          // threads for hist/place (occupancy fix, R6: 10%)
// NOTE: src packed in 17 bits -> requires N <= 131072 (N=100000 here)

// ---------------- bf16x2 helpers (pack with round-to-nearest-even) ---------
__device__ inline float blo(unsigned p) { return __uint_as_float(p << 16); }
__device__ inline float bhi(unsigned p) { return __uint_as_float(p & 0xffff0000u); }
__device__ inline unsigned bpack(float x, float y) {
    unsigned ux = __float_as_uint(x);
    unsigned uy = __float_as_uint(y);
    ux += 0x7fffu + ((ux >> 16) & 1u);
    uy += 0x7fffu + ((uy >> 16) & 1u);
    return (ux >> 16) | (uy & 0xffff0000u);
}

// ---------------------------------------------------------------------------
// Pass A: per-(block,bucket) LDS histogram — zero global atomics.
// Edge->block mapping MUST match place_kernel (same grid-stride).
// ---------------------------------------------------------------------------
__global__ __launch_bounds__(HIST_B)
void hist_kernel(const int* __restrict__ adj, int E,
                 int* __restrict__ hist, int NB) {
    extern __shared__ int lh[];
    for (int g = threadIdx.x; g < NB; g += blockDim.x) lh[g] = 0;
    __syncthreads();
    for (int e = blockIdx.x * blockDim.x + threadIdx.x; e < E;
         e += NBLK * blockDim.x) {
        int a = adj[e];
        int b = adj[E + e];
        atomicAdd(&lh[a >> BKT_SHIFT], 1);
        atomicAdd(&lh[b >> BKT_SHIFT], 1);
    }
    __syncthreads();
    for (int g = threadIdx.x; g < NB; g += blockDim.x)
        hist[g * NBLK + blockIdx.x] = lh[g];   // bucket-major for the scan
}

// --------------------------- prefix scan (3 stages) ------------------------
__global__ void scan_block_kernel(const int* __restrict__ src, int n,
                                  int* __restrict__ dst,
                                  int* __restrict__ blocksums) {
    __shared__ int tmp[SCAN_B];
    int i = blockIdx.x * SCAN_B + threadIdx.x;
    int v = (i < n) ? src[i] : 0;
    tmp[threadIdx.x] = v;
    __syncthreads();
    for (int off = 1; off < SCAN_B; off <<= 1) {
        int t = (threadIdx.x >= off) ? tmp[threadIdx.x - off] : 0;
        __syncthreads();
        tmp[threadIdx.x] += t;
        __syncthreads();
    }
    if (i < n) dst[i] = tmp[threadIdx.x] - v;           // exclusive
    if (threadIdx.x == SCAN_B - 1) blocksums[blockIdx.x] = tmp[SCAN_B - 1];
}

__global__ void scan_sums_kernel(int* __restrict__ blocksums, int nb) {
    __shared__ int tmp[1024];
    int v = (threadIdx.x < nb) ? blocksums[threadIdx.x] : 0;
    tmp[threadIdx.x] = v;
    __syncthreads();
    for (int off = 1; off < 1024; off <<= 1) {
        int t = (threadIdx.x >= off) ? tmp[threadIdx.x - off] : 0;
        __syncthreads();
        tmp[threadIdx.x] += t;
        __syncthreads();
    }
    if (threadIdx.x < nb) blocksums[threadIdx.x] = tmp[threadIdx.x] - v;  // exclusive
}

__global__ void scan_add_kernel(int* __restrict__ dst,
                                const int* __restrict__ blocksums,
                                int n, int total) {
    int i = blockIdx.x * blockDim.x + threadIdx.x;
    if (i < n) dst[i] += blocksums[i / SCAN_B];
    if (i == n) dst[n] = total;
}

// ---------------------------------------------------------------------------
// Pass C: placement. This block's records for bucket g land contiguously.
// record = (dstLocal << 17) | src
// ---------------------------------------------------------------------------
__global__ __launch_bounds__(HIST_B)
void place_kernel(const int* __restrict__ adj, int E,
                  const int* __restrict__ hist_s,
                  unsigned* __restrict__ pairs, int NB) {
    extern __shared__ int cur[];
    for (int g = threadIdx.x; g < NB; g += blockDim.x)
        cur[g] = hist_s[g * NBLK + blockIdx.x];
    __syncthreads();
    for (int e = blockIdx.x * blockDim.x + threadIdx.x; e < E;
         e += NBLK * blockDim.x) {
        int a = adj[e];
        int b = adj[E + e];
        int pb = atomicAdd(&cur[b >> BKT_SHIFT], 1);
        pairs[pb] = ((unsigned)(b & (BKT_G - 1)) << 17) | (unsigned)a;
        int pa = atomicAdd(&cur[a >> BKT_SHIFT], 1);
        pairs[pa] = ((unsigned)(a & (BKT_G - 1)) << 17) | (unsigned)b;
    }
}

// ---------------------------------------------------------------------------
// Pass D (one block per bucket): LDS-count 128 dstLocals -> deg/dinv/row_ptr
// coalesced, within-bucket csr scatter, AND fused xs0 = bf16(dinv*x0) for the
// bucket's nodes (init_xs dispatch eliminated).
// ---------------------------------------------------------------------------
__global__ void pass2_build_kernel(const unsigned* __restrict__ pairs,
                                   const int* __restrict__ hist_s,
                                   const float4* __restrict__ x,
                                   int* __restrict__ csr_src,
                                   int* __restrict__ row_ptr,
                                   int* __restrict__ deg,
                                   float* __restrict__ dinv,
                                   uint4* __restrict__ xs0,
                                   int N, int total_adj) {
    __shared__ int cnt[BKT_G];
    __shared__ int pre[BKT_G];
    __shared__ int cur[BKT_G];
    __shared__ float dv[BKT_G];
    int g = blockIdx.x;
    int base = g << BKT_SHIFT;
    int off = hist_s[(size_t)g * NBLK];
    int offn = (g + 1 < gridDim.x) ? hist_s[(size_t)(g + 1) * NBLK] : total_adj;
    int m = offn - off;
    if (threadIdx.x < BKT_G) cnt[threadIdx.x] = 0;
    __syncthreads();
    // phase 1: count dstLocal occurrences
    for (int i = threadIdx.x; i < m; i += blockDim.x)
        atomicAdd(&cnt[pairs[off + i] >> 17], 1);
    __syncthreads();
    // phase 2: inclusive LDS scan of cnt
    if (threadIdx.x < BKT_G) pre[threadIdx.x] = cnt[threadIdx.x];
    __syncthreads();
    for (int o = 1; o < BKT_G; o <<= 1) {
        int t = 0;
        if (threadIdx.x < BKT_G && threadIdx.x >= o) t = pre[threadIdx.x - o];
        __syncthreads();
        if (threadIdx.x < BKT_G) pre[threadIdx.x] += t;
        __syncthreads();
    }
    // phase 3: emit deg / dinv / row_ptr (coalesced), init cursors
    if (threadIdx.x < BKT_G) {
        int v = base + threadIdx.x;
        if (v < N) {
            int c = cnt[threadIdx.x];
            int start = off + pre[threadIdx.x] - c;   // exclusive
            float di = (c > 0) ? rsqrtf((float)c) : 0.0f;
            row_ptr[v] = start;
            deg[v] = c;
            dinv[v] = di;
            dv[threadIdx.x] = di;
            cur[threadIdx.x] = start;
        }
    }
    if (g == gridDim.x - 1 && threadIdx.x == 0) row_ptr[N] = total_adj;
    __syncthreads();
    // phase 4: scatter into csr window (L2-resident, LDS cursors)
    for (int i = threadIdx.x; i < m; i += blockDim.x) {
        unsigned p = pairs[off + i];
        int dl  = (int)(p >> 17);
        int src = (int)(p & 0x1ffffu);
        int pos = atomicAdd(&cur[dl], 1);
        csr_src[pos] = src;
    }
    // phase 5 (fused init): xs0 rows for this bucket's nodes
    for (int w = threadIdx.x; w < BKT_G * 8; w += blockDim.x) {
        int vl = w >> 3, sub = w & 7;
        int v = base + vl;
        if (v < N) {
            float di = dv[vl];
            float4 xa = x[(size_t)v * 16 + sub * 2];
            float4 xb = x[(size_t)v * 16 + sub * 2 + 1];
            uint4 o;
            o.x = bpack(di * xa.x, di * xa.y);
            o.y = bpack(di * xa.z, di * xa.w);
            o.z = bpack(di * xb.x, di * xb.y);
            o.w = bpack(di * xb.z, di * xb.w);
            xs0[(size_t)v * 8 + sub] = o;
        }
    }
}

// ------------------------------- SpMM --------------------------------------
// 32 lanes per node (2 nodes/wave). Software-pipelined: 2 neighbor slots per
// lane (j+nb, j+nb+4, step 8), index prefetch distance 1 -> 2 gathers + 2
// index loads in flight, breaking the serial csr->gather chain (R6: 1 VMEM
// per ~196 cyc/SIMD = latency-bound). Tails: clamped safe-load + mask-FMA.
__global__ void spmm_bf16_kernel(const int* __restrict__ row_ptr,
                                 const int* __restrict__ csr_src,
                                 const float* __restrict__ dinv,
                                 const uint4* __restrict__ xs_in,
                                 uint4* __restrict__ xs_out, int N) {
    int t = blockIdx.x * blockDim.x + threadIdx.x;
    int v = t >> 5;
    if (v >= N) return;
    int half = threadIdx.x & 31;
    int nb = half >> 3, sub = half & 7;
    int beg = row_ptr[v];
    int end = row_ptr[v + 1];
    float a0 = 0, a1 = 0, a2 = 0, a3 = 0, a4 = 0, a5 = 0, a6 = 0, a7 = 0;
    int i0 = beg + nb, i1 = beg + nb + 4;
    int s0 = (i0 < end) ? csr_src[i0] : -1;
    int s1 = (i1 < end) ? csr_src[i1] : -1;
    for (int j = beg; j < end; j += 8) {
        int ni0 = j + 8 + nb, ni1 = j + 12 + nb;
        int t0 = (ni0 < end) ? csr_src[ni0] : -1;
        int t1 = (ni1 < end) ? csr_src[ni1] : -1;
        uint4 p0 = xs_in[(size_t)(s0 >= 0 ? s0 : 0) * 8 + sub];
        uint4 p1 = xs_in[(size_t)(s1 >= 0 ? s1 : 0) * 8 + sub];
        float m0 = (s0 >= 0) ? 1.0f : 0.0f;
        float m1 = (s1 >= 0) ? 1.0f : 0.0f;
        a0 += m0 * blo(p0.x); a1 += m0 * bhi(p0.x);
        a2 += m0 * blo(p0.y); a3 += m0 * bhi(p0.y);
        a4 += m0 * blo(p0.z); a5 += m0 * bhi(p0.z);
        a6 += m0 * blo(p0.w); a7 += m0 * bhi(p0.w);
        a0 += m1 * blo(p1.x); a1 += m1 * bhi(p1.x);
        a2 += m1 * blo(p1.y); a3 += m1 * bhi(p1.y);
        a4 += m1 * blo(p1.z); a5 += m1 * bhi(p1.z);
        a6 += m1 * blo(p1.w); a7 += m1 * bhi(p1.w);
        s0 = t0; s1 = t1;
    }
    a0 += __shfl_xor(a0, 8);  a0 += __shfl_xor(a0, 16);
    a1 += __shfl_xor(a1, 8);  a1 += __shfl_xor(a1, 16);
    a2 += __shfl_xor(a2, 8);  a2 += __shfl_xor(a2, 16);
    a3 += __shfl_xor(a3, 8);  a3 += __shfl_xor(a3, 16);
    a4 += __shfl_xor(a4, 8);  a4 += __shfl_xor(a4, 16);
    a5 += __shfl_xor(a5, 8);  a5 += __shfl_xor(a5, 16);
    a6 += __shfl_xor(a6, 8);  a6 += __shfl_xor(a6, 16);
    a7 += __shfl_xor(a7, 8);  a7 += __shfl_xor(a7, 16);
    if (nb == 0) {
        float di = dinv[v];
        float d2 = di * di;
        uint4 o;
        o.x = bpack(d2 * a0, d2 * a1);
        o.y = bpack(d2 * a2, d2 * a3);
        o.z = bpack(d2 * a4, d2 * a5);
        o.w = bpack(d2 * a6, d2 * a7);
        xs_out[(size_t)v * 8 + sub] = o;
    }
}

// ---------------- final: out = 0.25*(x0 + sqrt(d)*(xs1+xs2+xs3)) -----------
__global__ void final_kernel(const float4* __restrict__ x,
                             const int* __restrict__ deg,
                             const uint4* __restrict__ xs1,
                             const uint4* __restrict__ xs2,
                             const uint4* __restrict__ xs3,
                             float4* __restrict__ out, int N) {
    int t = blockIdx.x * blockDim.x + threadIdx.x;
    int v = t >> 3, sub = t & 7;
    if (v >= N) return;
    size_t idx = (size_t)v * 8 + sub;
    uint4 p1 = xs1[idx], p2 = xs2[idx], p3 = xs3[idx];
    float rs = sqrtf((float)deg[v]);   // deg==0 -> 0, matches xs==0
    float s0 = blo(p1.x) + blo(p2.x) + blo(p3.x);
    float s1 = bhi(p1.x) + bhi(p2.x) + bhi(p3.x);
    float s2 = blo(p1.y) + blo(p2.y) + blo(p3.y);
    float s3 = bhi(p1.y) + bhi(p2.y) + bhi(p3.y);
    float s4 = blo(p1.z) + blo(p2.z) + blo(p3.z);
    float s5 = bhi(p1.z) + bhi(p2.z) + bhi(p3.z);
    float s6 = blo(p1.w) + blo(p2.w) + blo(p3.w);
    float s7 = bhi(p1.w) + bhi(p2.w) + bhi(p3.w);
    float4 xa = x[(size_t)v * 16 + sub * 2];
    float4 xb = x[(size_t)v * 16 + sub * 2 + 1];
    float4 oa, ob;
    oa.x = 0.25f * (xa.x + rs * s0);
    oa.y = 0.25f * (xa.y + rs * s1);
    oa.z = 0.25f * (xa.z + rs * s2);
    oa.w = 0.25f * (xa.w + rs * s3);
    ob.x = 0.25f * (xb.x + rs * s4);
    ob.y = 0.25f * (xb.y + rs * s5);
    ob.z = 0.25f * (xb.z + rs * s6);
    ob.w = 0.25f * (xb.w + rs * s7);
    out[(size_t)v * 16 + sub * 2]     = oa;
    out[(size_t)v * 16 + sub * 2 + 1] = ob;
}

extern "C" void kernel_launch(void* const* d_in, const int* in_sizes, int n_in,
                              void* d_out, int out_size, void* d_ws, size_t ws_size,
                              hipStream_t stream) {
    const float* x = (const float*)d_in[0];
    const int* adj = (const int*)d_in[1];
    float* out     = (float*)d_out;

    const int total_adj = in_sizes[1];   // 2*E entries in adj
    const int E = total_adj / 2;
    const int N = in_sizes[0] / DIM;
    const int NB = (N + BKT_G - 1) / BKT_G;   // dst buckets
    const int nhist = NB * NBLK;

    size_t BUF = (size_t)total_adj * 4;
    size_t xsb = (size_t)N * 32 * 4;
    if (xsb > BUF) BUF = xsb;
    BUF = (BUF + 255) & ~(size_t)255;

    char* ws = (char*)d_ws;
    int*      deg     = (int*)(ws);                               // 400KB
    float*    dinv    = (float*)(ws + (size_t)512 * 1024);        // 400KB
    int*      row_ptr = (int*)(ws + (size_t)1024 * 1024);         // 400KB+4
    int*      bsums   = (int*)(ws + (size_t)1536 * 1024);         // 1024 ints
    int*      hist    = (int*)(ws + (size_t)1600 * 1024);         // ~801KB
    int*      hist_s  = (int*)(ws + (size_t)2432 * 1024);         // ~801KB
    char*     big     = ws + (size_t)3264 * 1024;
    int*      csr_src = (int*)(big);
    unsigned* pairs   = (unsigned*)(big + BUF);   // dead after pass2
    uint4*    xs0     = (uint4*)(big + BUF);      // aliases pairs: written in
                                                  // pass2 phase5 AFTER phase4's
                                                  // last pairs read? NO — keep
                                                  // xs0 separate for safety:
    uint4*    xs1     = (uint4*)(big + 2 * BUF);
    uint4*    xs2     = (uint4*)(big + 3 * BUF);
    uint4*    xs3     = (uint4*)(big + 4 * BUF);
    uint4*    xs0_s   = (uint4*)(big + 5 * BUF);  // non-aliased xs0

    const int B = 256;

    // 1) per-(block,bucket) histogram — no global atomics
    hist_kernel<<<NBLK, HIST_B, NB * sizeof(int), stream>>>(adj, E, hist, NB);

    // 2) hist_s = exclusive_scan(hist)
    const int nscan2 = (nhist + SCAN_B - 1) / SCAN_B;
    scan_block_kernel<<<nscan2, SCAN_B, 0, stream>>>(hist, nhist, hist_s, bsums);
    scan_sums_kernel<<<1, 1024, 0, stream>>>(bsums, nscan2);
    scan_add_kernel<<<(nhist + 1 + B - 1) / B, B, 0, stream>>>(hist_s, bsums, nhist, total_adj);

    // 3) placement into bucket-grouped pairs
    place_kernel<<<NBLK, HIST_B, NB * sizeof(int), stream>>>(adj, E, hist_s, pairs, NB);

    // 4) per-bucket: deg/dinv/row_ptr + csr scatter + fused xs0 init
    pass2_build_kernel<<<NB, B, 0, stream>>>(pairs, hist_s, (const float4*)x,
                                             csr_src, row_ptr, deg, dinv,
                                             xs0_s, N, total_adj);

    // 5) three propagation layers (bf16 buffers, fp32 accumulate)
    const int nblocks32 = (int)(((long long)N * 32 + B - 1) / B);
    spmm_bf16_kernel<<<nblocks32, B, 0, stream>>>(row_ptr, csr_src, dinv, xs0_s, xs1, N);
    spmm_bf16_kernel<<<nblocks32, B, 0, stream>>>(row_ptr, csr_src, dinv, xs1, xs2, N);
    spmm_bf16_kernel<<<nblocks32, B, 0, stream>>>(row_ptr, csr_src, dinv, xs2, xs3, N);

    // 6) out = 0.25*(x0 + sqrt(d)*(xs1+xs2+xs3))
    const int nblocks8 = (int)(((long long)N * 8 + B - 1) / B);
    final_kernel<<<nblocks8, B, 0, stream>>>((const float4*)x, deg, xs1, xs2, xs3,
                                             (float4*)out, N);
}

// Round 8
// 300.858 us; speedup vs baseline: 4.0045x; 1.0043x over previous
//
#include <hip/hip_runtime.h>

#define DIM 64
#define SCAN_B 256
#define BKT_SHIFT 7          // 128 nodes per bucket
#define BKT_G 128
#define NBLK 256             // blocks in histogram/placement passes (fixed: scan layout)
#define HIST_B 1024          // threads for hist/place (occupancy fix, R6: 10%)
// NOTE: src packed in 17 bits -> requires N <= 131072 (N=100000 here)

// ---------------- bf16x2 helpers (pack with round-to-nearest-even) ---------
__device__ inline float blo(unsigned p) { return __uint_as_float(p << 16); }
__device__ inline float bhi(unsigned p) { return __uint_as_float(p & 0xffff0000u); }
__device__ inline unsigned bpack(float x, float y) {
    unsigned ux = __float_as_uint(x);
    unsigned uy = __float_as_uint(y);
    ux += 0x7fffu + ((ux >> 16) & 1u);
    uy += 0x7fffu + ((uy >> 16) & 1u);
    return (ux >> 16) | (uy & 0xffff0000u);
}

// ---------------------------------------------------------------------------
// Pass A: per-(block,bucket) LDS histogram — zero global atomics.
// Edge->block mapping MUST match place_kernel (same grid-stride).
// ---------------------------------------------------------------------------
__global__ __launch_bounds__(HIST_B)
void hist_kernel(const int* __restrict__ adj, int E,
                 int* __restrict__ hist, int NB) {
    extern __shared__ int lh[];
    for (int g = threadIdx.x; g < NB; g += blockDim.x) lh[g] = 0;
    __syncthreads();
    for (int e = blockIdx.x * blockDim.x + threadIdx.x; e < E;
         e += NBLK * blockDim.x) {
        int a = adj[e];
        int b = adj[E + e];
        atomicAdd(&lh[a >> BKT_SHIFT], 1);
        atomicAdd(&lh[b >> BKT_SHIFT], 1);
    }
    __syncthreads();
    for (int g = threadIdx.x; g < NB; g += blockDim.x)
        hist[g * NBLK + blockIdx.x] = lh[g];   // bucket-major for the scan
}

// --------------------------- prefix scan (3 stages) ------------------------
__global__ void scan_block_kernel(const int* __restrict__ src, int n,
                                  int* __restrict__ dst,
                                  int* __restrict__ blocksums) {
    __shared__ int tmp[SCAN_B];
    int i = blockIdx.x * SCAN_B + threadIdx.x;
    int v = (i < n) ? src[i] : 0;
    tmp[threadIdx.x] = v;
    __syncthreads();
    for (int off = 1; off < SCAN_B; off <<= 1) {
        int t = (threadIdx.x >= off) ? tmp[threadIdx.x - off] : 0;
        __syncthreads();
        tmp[threadIdx.x] += t;
        __syncthreads();
    }
    if (i < n) dst[i] = tmp[threadIdx.x] - v;           // exclusive
    if (threadIdx.x == SCAN_B - 1) blocksums[blockIdx.x] = tmp[SCAN_B - 1];
}

__global__ void scan_sums_kernel(int* __restrict__ blocksums, int nb) {
    __shared__ int tmp[1024];
    int v = (threadIdx.x < nb) ? blocksums[threadIdx.x] : 0;
    tmp[threadIdx.x] = v;
    __syncthreads();
    for (int off = 1; off < 1024; off <<= 1) {
        int t = (threadIdx.x >= off) ? tmp[threadIdx.x - off] : 0;
        __syncthreads();
        tmp[threadIdx.x] += t;
        __syncthreads();
    }
    if (threadIdx.x < nb) blocksums[threadIdx.x] = tmp[threadIdx.x] - v;  // exclusive
}

__global__ void scan_add_kernel(int* __restrict__ dst,
                                const int* __restrict__ blocksums,
                                int n, int total) {
    int i = blockIdx.x * blockDim.x + threadIdx.x;
    if (i < n) dst[i] += blocksums[i / SCAN_B];
    if (i == n) dst[n] = total;
}

// ---------------------------------------------------------------------------
// Pass C: placement. This block's records for bucket g land contiguously.
// record = (dstLocal << 17) | src
// ---------------------------------------------------------------------------
__global__ __launch_bounds__(HIST_B)
void place_kernel(const int* __restrict__ adj, int E,
                  const int* __restrict__ hist_s,
                  unsigned* __restrict__ pairs, int NB) {
    extern __shared__ int cur[];
    for (int g = threadIdx.x; g < NB; g += blockDim.x)
        cur[g] = hist_s[g * NBLK + blockIdx.x];
    __syncthreads();
    for (int e = blockIdx.x * blockDim.x + threadIdx.x; e < E;
         e += NBLK * blockDim.x) {
        int a = adj[e];
        int b = adj[E + e];
        int pb = atomicAdd(&cur[b >> BKT_SHIFT], 1);
        pairs[pb] = ((unsigned)(b & (BKT_G - 1)) << 17) | (unsigned)a;
        int pa = atomicAdd(&cur[a >> BKT_SHIFT], 1);
        pairs[pa] = ((unsigned)(a & (BKT_G - 1)) << 17) | (unsigned)b;
    }
}

// ---------------------------------------------------------------------------
// Pass D (one block per bucket): LDS-count 128 dstLocals -> deg/dinv/row_ptr
// coalesced, within-bucket csr scatter, AND fused xs0 = bf16(dinv*x0).
// ---------------------------------------------------------------------------
__global__ void pass2_build_kernel(const unsigned* __restrict__ pairs,
                                   const int* __restrict__ hist_s,
                                   const float4* __restrict__ x,
                                   int* __restrict__ csr_src,
                                   int* __restrict__ row_ptr,
                                   int* __restrict__ deg,
                                   float* __restrict__ dinv,
                                   uint4* __restrict__ xs0,
                                   int N, int total_adj) {
    __shared__ int cnt[BKT_G];
    __shared__ int pre[BKT_G];
    __shared__ int cur[BKT_G];
    __shared__ float dv[BKT_G];
    int g = blockIdx.x;
    int base = g << BKT_SHIFT;
    int off = hist_s[(size_t)g * NBLK];
    int offn = (g + 1 < gridDim.x) ? hist_s[(size_t)(g + 1) * NBLK] : total_adj;
    int m = offn - off;
    if (threadIdx.x < BKT_G) cnt[threadIdx.x] = 0;
    __syncthreads();
    // phase 1: count dstLocal occurrences
    for (int i = threadIdx.x; i < m; i += blockDim.x)
        atomicAdd(&cnt[pairs[off + i] >> 17], 1);
    __syncthreads();
    // phase 2: inclusive LDS scan of cnt
    if (threadIdx.x < BKT_G) pre[threadIdx.x] = cnt[threadIdx.x];
    __syncthreads();
    for (int o = 1; o < BKT_G; o <<= 1) {
        int t = 0;
        if (threadIdx.x < BKT_G && threadIdx.x >= o) t = pre[threadIdx.x - o];
        __syncthreads();
        if (threadIdx.x < BKT_G) pre[threadIdx.x] += t;
        __syncthreads();
    }
    // phase 3: emit deg / dinv / row_ptr (coalesced), init cursors
    if (threadIdx.x < BKT_G) {
        int v = base + threadIdx.x;
        if (v < N) {
            int c = cnt[threadIdx.x];
            int start = off + pre[threadIdx.x] - c;   // exclusive
            float di = (c > 0) ? rsqrtf((float)c) : 0.0f;
            row_ptr[v] = start;
            deg[v] = c;
            dinv[v] = di;
            dv[threadIdx.x] = di;
            cur[threadIdx.x] = start;
        }
    }
    if (g == gridDim.x - 1 && threadIdx.x == 0) row_ptr[N] = total_adj;
    __syncthreads();
    // phase 4: scatter into csr window (L2-resident, LDS cursors)
    for (int i = threadIdx.x; i < m; i += blockDim.x) {
        unsigned p = pairs[off + i];
        int dl  = (int)(p >> 17);
        int src = (int)(p & 0x1ffffu);
        int pos = atomicAdd(&cur[dl], 1);
        csr_src[pos] = src;
    }
    // phase 5 (fused init): xs0 rows for this bucket's nodes
    for (int w = threadIdx.x; w < BKT_G * 8; w += blockDim.x) {
        int vl = w >> 3, sub = w & 7;
        int v = base + vl;
        if (v < N) {
            float di = dv[vl];
            float4 xa = x[(size_t)v * 16 + sub * 2];
            float4 xb = x[(size_t)v * 16 + sub * 2 + 1];
            uint4 o;
            o.x = bpack(di * xa.x, di * xa.y);
            o.y = bpack(di * xa.z, di * xa.w);
            o.z = bpack(di * xb.x, di * xb.y);
            o.w = bpack(di * xb.z, di * xb.w);
            xs0[(size_t)v * 8 + sub] = o;
        }
    }
}

// --------------------- SpMM accumulation (shared body) ---------------------
// 32 lanes per node: 16 neighbors/iter (4 gather slots per lane), maskless
// full-group main loop with index prefetch distance 1 (4 gathers + 4 index
// loads in flight), short masked tail. Result: per-lane partial sums a0..a7,
// folded across the 4 neighbor groups with shfl_xor(8,16).
#define SPMM_ACCUM_BODY                                                        \
    int half = threadIdx.x & 31;                                               \
    int nb = half >> 3, sub = half & 7;                                        \
    int beg = row_ptr[v];                                                      \
    int end = row_ptr[v + 1];                                                  \
    int full = (end - beg) >> 4;                                               \
    float a0 = 0, a1 = 0, a2 = 0, a3 = 0, a4 = 0, a5 = 0, a6 = 0, a7 = 0;      \
    int j = beg;                                                               \
    int s0 = 0, s1 = 0, s2 = 0, s3 = 0;                                        \
    if (full > 0) {                                                            \
        int b = j + 4 * nb;                                                    \
        s0 = csr_src[b];     s1 = csr_src[b + 1];                              \
        s2 = csr_src[b + 2]; s3 = csr_src[b + 3];                              \
    }                                                                          \
    for (int it = 0; it < full; ++it) {                                        \
        int jn = j + 16;                                                       \
        int t0 = 0, t1 = 0, t2 = 0, t3 = 0;                                    \
        if (it + 1 < full) {                                                   \
            int b = jn + 4 * nb;                                               \
            t0 = csr_src[b];     t1 = csr_src[b + 1];                          \
            t2 = csr_src[b + 2]; t3 = csr_src[b + 3];                          \
        }                                                                      \
        uint4 p0 = xs_in[(size_t)s0 * 8 + sub];                                \
        uint4 p1 = xs_in[(size_t)s1 * 8 + sub];                                \
        uint4 p2 = xs_in[(size_t)s2 * 8 + sub];                                \
        uint4 p3 = xs_in[(size_t)s3 * 8 + sub];                                \
        a0 += (blo(p0.x) + blo(p1.x)) + (blo(p2.x) + blo(p3.x));               \
        a1 += (bhi(p0.x) + bhi(p1.x)) + (bhi(p2.x) + bhi(p3.x));               \
        a2 += (blo(p0.y) + blo(p1.y)) + (blo(p2.y) + blo(p3.y));               \
        a3 += (bhi(p0.y) + bhi(p1.y)) + (bhi(p2.y) + bhi(p3.y));               \
        a4 += (blo(p0.z) + blo(p1.z)) + (blo(p2.z) + blo(p3.z));               \
        a5 += (bhi(p0.z) + bhi(p1.z)) + (bhi(p2.z) + bhi(p3.z));               \
        a6 += (blo(p0.w) + blo(p1.w)) + (blo(p2.w) + blo(p3.w));               \
        a7 += (bhi(p0.w) + bhi(p1.w)) + (bhi(p2.w) + bhi(p3.w));               \
        s0 = t0; s1 = t1; s2 = t2; s3 = t3;                                    \
        j = jn;                                                                \
    }                                                                          \
    for (int idx = j + nb; idx < end; idx += 4) {                              \
        int s = csr_src[idx];                                                  \
        uint4 p = xs_in[(size_t)s * 8 + sub];                                  \
        a0 += blo(p.x); a1 += bhi(p.x);                                        \
        a2 += blo(p.y); a3 += bhi(p.y);                                        \
        a4 += blo(p.z); a5 += bhi(p.z);                                        \
        a6 += blo(p.w); a7 += bhi(p.w);                                        \
    }                                                                          \
    a0 += __shfl_xor(a0, 8);  a0 += __shfl_xor(a0, 16);                        \
    a1 += __shfl_xor(a1, 8);  a1 += __shfl_xor(a1, 16);                        \
    a2 += __shfl_xor(a2, 8);  a2 += __shfl_xor(a2, 16);                        \
    a3 += __shfl_xor(a3, 8);  a3 += __shfl_xor(a3, 16);                        \
    a4 += __shfl_xor(a4, 8);  a4 += __shfl_xor(a4, 16);                        \
    a5 += __shfl_xor(a5, 8);  a5 += __shfl_xor(a5, 16);                        \
    a6 += __shfl_xor(a6, 8);  a6 += __shfl_xor(a6, 16);                        \
    a7 += __shfl_xor(a7, 8);  a7 += __shfl_xor(a7, 16);

// Layers 1,2: xs_out = bf16(dinv^2 * acc)
__global__ void spmm_bf16_kernel(const int* __restrict__ row_ptr,
                                 const int* __restrict__ csr_src,
                                 const float* __restrict__ dinv,
                                 const uint4* __restrict__ xs_in,
                                 uint4* __restrict__ xs_out, int N) {
    int t = blockIdx.x * blockDim.x + threadIdx.x;
    int v = t >> 5;
    if (v >= N) return;
    SPMM_ACCUM_BODY
    if (nb == 0) {
        float di = dinv[v];
        float d2 = di * di;
        uint4 o;
        o.x = bpack(d2 * a0, d2 * a1);
        o.y = bpack(d2 * a2, d2 * a3);
        o.z = bpack(d2 * a4, d2 * a5);
        o.w = bpack(d2 * a6, d2 * a7);
        xs_out[(size_t)v * 8 + sub] = o;
    }
}

// Layer 3 fused with final:
//   y3 = dinv*acc (fp32, no bf16 round-trip)
//   out = 0.25*(x0 + rs*(xs1+xs2) + y3),  rs = sqrt(deg)
__global__ void spmm_last_kernel(const int* __restrict__ row_ptr,
                                 const int* __restrict__ csr_src,
                                 const float* __restrict__ dinv,
                                 const int* __restrict__ deg,
                                 const uint4* __restrict__ xs_in,   // xs2
                                 const uint4* __restrict__ xs1,
                                 const float4* __restrict__ x,
                                 float4* __restrict__ out, int N) {
    int t = blockIdx.x * blockDim.x + threadIdx.x;
    int v = t >> 5;
    if (v >= N) return;
    SPMM_ACCUM_BODY
    if (nb == 0) {
        float di = dinv[v];
        float rs = sqrtf((float)deg[v]);   // deg==0 -> 0, matches xs==0
        size_t idx = (size_t)v * 8 + sub;
        uint4 q1 = xs1[idx];
        uint4 q2 = xs_in[idx];
        float4 xa = x[(size_t)v * 16 + sub * 2];
        float4 xb = x[(size_t)v * 16 + sub * 2 + 1];
        float4 oa, ob;
        oa.x = 0.25f * (xa.x + rs * (blo(q1.x) + blo(q2.x)) + di * a0);
        oa.y = 0.25f * (xa.y + rs * (bhi(q1.x) + bhi(q2.x)) + di * a1);
        oa.z = 0.25f * (xa.z + rs * (blo(q1.y) + blo(q2.y)) + di * a2);
        oa.w = 0.25f * (xa.w + rs * (bhi(q1.y) + bhi(q2.y)) + di * a3);
        ob.x = 0.25f * (xb.x + rs * (blo(q1.z) + blo(q2.z)) + di * a4);
        ob.y = 0.25f * (xb.y + rs * (bhi(q1.z) + bhi(q2.z)) + di * a5);
        ob.z = 0.25f * (xb.z + rs * (blo(q1.w) + blo(q2.w)) + di * a6);
        ob.w = 0.25f * (xb.w + rs * (bhi(q1.w) + bhi(q2.w)) + di * a7);
        out[(size_t)v * 16 + sub * 2]     = oa;
        out[(size_t)v * 16 + sub * 2 + 1] = ob;
    }
}

extern "C" void kernel_launch(void* const* d_in, const int* in_sizes, int n_in,
                              void* d_out, int out_size, void* d_ws, size_t ws_size,
                              hipStream_t stream) {
    const float* x = (const float*)d_in[0];
    const int* adj = (const int*)d_in[1];
    float* out     = (float*)d_out;

    const int total_adj = in_sizes[1];   // 2*E entries in adj
    const int E = total_adj / 2;
    const int N = in_sizes[0] / DIM;
    const int NB = (N + BKT_G - 1) / BKT_G;   // dst buckets
    const int nhist = NB * NBLK;

    size_t BUF = (size_t)total_adj * 4;
    size_t xsb = (size_t)N * 32 * 4;
    if (xsb > BUF) BUF = xsb;
    BUF = (BUF + 255) & ~(size_t)255;

    char* ws = (char*)d_ws;
    int*      deg     = (int*)(ws);                               // 400KB
    float*    dinv    = (float*)(ws + (size_t)512 * 1024);        // 400KB
    int*      row_ptr = (int*)(ws + (size_t)1024 * 1024);         // 400KB+4
    int*      bsums   = (int*)(ws + (size_t)1536 * 1024);         // 1024 ints
    int*      hist    = (int*)(ws + (size_t)1600 * 1024);         // ~801KB
    int*      hist_s  = (int*)(ws + (size_t)2432 * 1024);         // ~801KB
    char*     big     = ws + (size_t)3264 * 1024;
    int*      csr_src = (int*)(big);
    unsigned* pairs   = (unsigned*)(big + BUF);     // dead after pass2
    uint4*    xs0     = (uint4*)(big + 2 * BUF);
    uint4*    xs1     = (uint4*)(big + 3 * BUF);
    uint4*    xs2     = (uint4*)(big + 4 * BUF);

    const int B = 256;

    // 1) per-(block,bucket) histogram — no global atomics
    hist_kernel<<<NBLK, HIST_B, NB * sizeof(int), stream>>>(adj, E, hist, NB);

    // 2) hist_s = exclusive_scan(hist)
    const int nscan2 = (nhist + SCAN_B - 1) / SCAN_B;
    scan_block_kernel<<<nscan2, SCAN_B, 0, stream>>>(hist, nhist, hist_s, bsums);
    scan_sums_kernel<<<1, 1024, 0, stream>>>(bsums, nscan2);
    scan_add_kernel<<<(nhist + 1 + B - 1) / B, B, 0, stream>>>(hist_s, bsums, nhist, total_adj);

    // 3) placement into bucket-grouped pairs
    place_kernel<<<NBLK, HIST_B, NB * sizeof(int), stream>>>(adj, E, hist_s, pairs, NB);

    // 4) per-bucket: deg/dinv/row_ptr + csr scatter + fused xs0 init
    pass2_build_kernel<<<NB, B, 0, stream>>>(pairs, hist_s, (const float4*)x,
                                             csr_src, row_ptr, deg, dinv,
                                             xs0, N, total_adj);

    // 5) layers 1,2 then fused layer3+final
    const int nblocks32 = (int)(((long long)N * 32 + B - 1) / B);
    spmm_bf16_kernel<<<nblocks32, B, 0, stream>>>(row_ptr, csr_src, dinv, xs0, xs1, N);
    spmm_bf16_kernel<<<nblocks32, B, 0, stream>>>(row_ptr, csr_src, dinv, xs1, xs2, N);
    spmm_last_kernel<<<nblocks32, B, 0, stream>>>(row_ptr, csr_src, dinv, deg,
                                                  xs2, xs1, (const float4*)x,
                                                  (float4*)out, N);
}

// Round 9
// 294.479 us; speedup vs baseline: 4.0912x; 1.0217x over previous
//
#include <hip/hip_runtime.h>

#define DIM 64
#define SCAN_B 256
#define BKT_SHIFT 7          // 128 nodes per bucket
#define BKT_G 128
#define NBLK 256             // blocks in hist/place (MUST == SCAN_B: bucket==chunk)
#define HIST_B 1024          // threads for hist/place
#define NREP 4               // LDS histogram replicas (contention /4)
#define RCAP 20              // records held in regs per pass2 thread (m<=5120)
// NOTE: src packed in 17 bits -> requires N <= 131072 (N=100000 here)

// ---------------- bf16x2 helpers (pack with round-to-nearest-even) ---------
__device__ inline float blo(unsigned p) { return __uint_as_float(p << 16); }
__device__ inline float bhi(unsigned p) { return __uint_as_float(p & 0xffff0000u); }
__device__ inline unsigned bpack(float x, float y) {
    unsigned ux = __float_as_uint(x);
    unsigned uy = __float_as_uint(y);
    ux += 0x7fffu + ((ux >> 16) & 1u);
    uy += 0x7fffu + ((uy >> 16) & 1u);
    return (ux >> 16) | (uy & 0xffff0000u);
}

// ---------------------------------------------------------------------------
// Pass A: per-(block,bucket) LDS histogram, 4 replicas, int4 edge loads.
// Edge->block mapping MUST match place_kernel exactly (same grid-stride).
// ---------------------------------------------------------------------------
__global__ __launch_bounds__(HIST_B)
void hist_kernel(const int* __restrict__ adj, int E,
                 int* __restrict__ hist, int NB) {
    extern __shared__ int lh[];            // NREP * NB
    for (int g = threadIdx.x; g < NREP * NB; g += blockDim.x) lh[g] = 0;
    __syncthreads();
    const int rep = (threadIdx.x & (NREP - 1)) * NB;
    const int n4 = E >> 2;
    const int4* srcs = (const int4*)adj;
    const int4* dsts = (const int4*)(adj + E);
    for (int i = blockIdx.x * blockDim.x + threadIdx.x; i < n4;
         i += NBLK * blockDim.x) {
        int4 a = srcs[i];
        int4 b = dsts[i];
        atomicAdd(&lh[rep + (a.x >> BKT_SHIFT)], 1);
        atomicAdd(&lh[rep + (a.y >> BKT_SHIFT)], 1);
        atomicAdd(&lh[rep + (a.z >> BKT_SHIFT)], 1);
        atomicAdd(&lh[rep + (a.w >> BKT_SHIFT)], 1);
        atomicAdd(&lh[rep + (b.x >> BKT_SHIFT)], 1);
        atomicAdd(&lh[rep + (b.y >> BKT_SHIFT)], 1);
        atomicAdd(&lh[rep + (b.z >> BKT_SHIFT)], 1);
        atomicAdd(&lh[rep + (b.w >> BKT_SHIFT)], 1);
    }
    if (blockIdx.x == 0) {                 // scalar tail (E%4), block 0 only
        for (int e = (n4 << 2) + threadIdx.x; e < E; e += blockDim.x) {
            atomicAdd(&lh[rep + (adj[e] >> BKT_SHIFT)], 1);
            atomicAdd(&lh[rep + (adj[E + e] >> BKT_SHIFT)], 1);
        }
    }
    __syncthreads();
    for (int g = threadIdx.x; g < NB; g += blockDim.x)
        hist[g * NBLK + blockIdx.x] =
            lh[g] + lh[NB + g] + lh[2 * NB + g] + lh[3 * NB + g];
}

// --------------------------- prefix scan (2 stages) ------------------------
// NBLK == SCAN_B  =>  each bucket's 256 counters are exactly one scan chunk:
// bucket base offset == bsums[g], and hist_s[g*256] == 0. scan_add removed —
// consumers add bsums themselves.
__global__ void scan_block_kernel(const int* __restrict__ src, int n,
                                  int* __restrict__ dst,
                                  int* __restrict__ blocksums) {
    __shared__ int tmp[SCAN_B];
    int i = blockIdx.x * SCAN_B + threadIdx.x;
    int v = (i < n) ? src[i] : 0;
    tmp[threadIdx.x] = v;
    __syncthreads();
    for (int off = 1; off < SCAN_B; off <<= 1) {
        int t = (threadIdx.x >= off) ? tmp[threadIdx.x - off] : 0;
        __syncthreads();
        tmp[threadIdx.x] += t;
        __syncthreads();
    }
    if (i < n) dst[i] = tmp[threadIdx.x] - v;           // chunk-exclusive
    if (threadIdx.x == SCAN_B - 1) blocksums[blockIdx.x] = tmp[SCAN_B - 1];
}

__global__ void scan_sums_kernel(int* __restrict__ blocksums, int nb) {
    __shared__ int tmp[1024];
    int v = (threadIdx.x < nb) ? blocksums[threadIdx.x] : 0;
    tmp[threadIdx.x] = v;
    __syncthreads();
    for (int off = 1; off < 1024; off <<= 1) {
        int t = (threadIdx.x >= off) ? tmp[threadIdx.x - off] : 0;
        __syncthreads();
        tmp[threadIdx.x] += t;
        __syncthreads();
    }
    if (threadIdx.x < nb) blocksums[threadIdx.x] = tmp[threadIdx.x] - v;  // exclusive
}

// ---------------------------------------------------------------------------
// Pass C: placement, int4 edge loads, scan fix-up fused (cur = hist_s+bsums).
// record = (dstLocal << 17) | src
// ---------------------------------------------------------------------------
__global__ __launch_bounds__(HIST_B)
void place_kernel(const int* __restrict__ adj, int E,
                  const int* __restrict__ hist_s,
                  const int* __restrict__ bsums,
                  unsigned* __restrict__ pairs, int NB) {
    extern __shared__ int cur[];
    for (int g = threadIdx.x; g < NB; g += blockDim.x)
        cur[g] = hist_s[g * NBLK + blockIdx.x] + bsums[g];
    __syncthreads();
    const int n4 = E >> 2;
    const int4* srcs = (const int4*)adj;
    const int4* dsts = (const int4*)(adj + E);
    for (int i = blockIdx.x * blockDim.x + threadIdx.x; i < n4;
         i += NBLK * blockDim.x) {
        int4 a = srcs[i];
        int4 b = dsts[i];
        int p;
        p = atomicAdd(&cur[b.x >> BKT_SHIFT], 1);
        pairs[p] = ((unsigned)(b.x & (BKT_G - 1)) << 17) | (unsigned)a.x;
        p = atomicAdd(&cur[a.x >> BKT_SHIFT], 1);
        pairs[p] = ((unsigned)(a.x & (BKT_G - 1)) << 17) | (unsigned)b.x;
        p = atomicAdd(&cur[b.y >> BKT_SHIFT], 1);
        pairs[p] = ((unsigned)(b.y & (BKT_G - 1)) << 17) | (unsigned)a.y;
        p = atomicAdd(&cur[a.y >> BKT_SHIFT], 1);
        pairs[p] = ((unsigned)(a.y & (BKT_G - 1)) << 17) | (unsigned)b.y;
        p = atomicAdd(&cur[b.z >> BKT_SHIFT], 1);
        pairs[p] = ((unsigned)(b.z & (BKT_G - 1)) << 17) | (unsigned)a.z;
        p = atomicAdd(&cur[a.z >> BKT_SHIFT], 1);
        pairs[p] = ((unsigned)(a.z & (BKT_G - 1)) << 17) | (unsigned)b.z;
        p = atomicAdd(&cur[b.w >> BKT_SHIFT], 1);
        pairs[p] = ((unsigned)(b.w & (BKT_G - 1)) << 17) | (unsigned)a.w;
        p = atomicAdd(&cur[a.w >> BKT_SHIFT], 1);
        pairs[p] = ((unsigned)(a.w & (BKT_G - 1)) << 17) | (unsigned)b.w;
    }
    if (blockIdx.x == 0) {                 // scalar tail, same rule as hist
        for (int e = (n4 << 2) + threadIdx.x; e < E; e += blockDim.x) {
            int a = adj[e];
            int b = adj[E + e];
            int p1 = atomicAdd(&cur[b >> BKT_SHIFT], 1);
            pairs[p1] = ((unsigned)(b & (BKT_G - 1)) << 17) | (unsigned)a;
            int p2 = atomicAdd(&cur[a >> BKT_SHIFT], 1);
            pairs[p2] = ((unsigned)(a & (BKT_G - 1)) << 17) | (unsigned)b;
        }
    }
}

// ---------------------------------------------------------------------------
// Pass D (one block of 256 per bucket): single pairs read — records held in
// registers between count phase and scatter phase (RCAP=20 unrolled, covers
// m<=5120; Poisson(4096,σ64) max ≈ 4400; re-read fallback beyond). Emits
// deg/dinv/row_ptr coalesced + csr scatter + fused xs0 = bf16(dinv*x0).
// ---------------------------------------------------------------------------
__global__ __launch_bounds__(256)
void pass2_build_kernel(const unsigned* __restrict__ pairs,
                        const int* __restrict__ bsums,
                        const float4* __restrict__ x,
                        int* __restrict__ csr_src,
                        int* __restrict__ row_ptr,
                        int* __restrict__ deg,
                        float* __restrict__ dinv,
                        uint4* __restrict__ xs0,
                        int N, int NB, int total_adj) {
    __shared__ int cnt[BKT_G];
    __shared__ int pre[BKT_G];
    __shared__ int cur[BKT_G];
    __shared__ float dv[BKT_G];
    int g = blockIdx.x;
    int base = g << BKT_SHIFT;
    int off  = bsums[g];                              // hist_s[g*256] == 0
    int offn = (g + 1 < NB) ? bsums[g + 1] : total_adj;
    int m = offn - off;
    if (threadIdx.x < BKT_G) cnt[threadIdx.x] = 0;
    __syncthreads();
    // phase 1: count dstLocal occurrences, retain records in registers
    unsigned rec[RCAP];
    int ibase = off + threadIdx.x;
#pragma unroll
    for (int k = 0; k < RCAP; ++k) {
        int i = ibase + k * 256;
        unsigned p = 0;
        if (i < offn) {
            p = pairs[i];
            atomicAdd(&cnt[p >> 17], 1);
        }
        rec[k] = p;
    }
    for (int i = ibase + RCAP * 256; i < offn; i += 256)   // overflow fallback
        atomicAdd(&cnt[pairs[i] >> 17], 1);
    __syncthreads();
    // phase 2: inclusive LDS scan of cnt
    if (threadIdx.x < BKT_G) pre[threadIdx.x] = cnt[threadIdx.x];
    __syncthreads();
    for (int o = 1; o < BKT_G; o <<= 1) {
        int t = 0;
        if (threadIdx.x < BKT_G && threadIdx.x >= o) t = pre[threadIdx.x - o];
        __syncthreads();
        if (threadIdx.x < BKT_G) pre[threadIdx.x] += t;
        __syncthreads();
    }
    // phase 3: emit deg / dinv / row_ptr (coalesced), init cursors
    if (threadIdx.x < BKT_G) {
        int v = base + threadIdx.x;
        if (v < N) {
            int c = cnt[threadIdx.x];
            int start = off + pre[threadIdx.x] - c;   // exclusive
            float di = (c > 0) ? rsqrtf((float)c) : 0.0f;
            row_ptr[v] = start;
            deg[v] = c;
            dinv[v] = di;
            dv[threadIdx.x] = di;
            cur[threadIdx.x] = start;
        }
    }
    if (g == NB - 1 && threadIdx.x == 0) row_ptr[N] = total_adj;
    __syncthreads();
    // phase 4: scatter from registers into csr window (L2-resident)
#pragma unroll
    for (int k = 0; k < RCAP; ++k) {
        int i = ibase + k * 256;
        if (i < offn) {
            unsigned p = rec[k];
            int pos = atomicAdd(&cur[p >> 17], 1);
            csr_src[pos] = (int)(p & 0x1ffffu);
        }
    }
    for (int i = ibase + RCAP * 256; i < offn; i += 256) { // overflow fallback
        unsigned p = pairs[i];
        int pos = atomicAdd(&cur[p >> 17], 1);
        csr_src[pos] = (int)(p & 0x1ffffu);
    }
    // phase 5 (fused init): xs0 rows for this bucket's nodes
    for (int w = threadIdx.x; w < BKT_G * 8; w += blockDim.x) {
        int vl = w >> 3, sub = w & 7;
        int v = base + vl;
        if (v < N) {
            float di = dv[vl];
            float4 xa = x[(size_t)v * 16 + sub * 2];
            float4 xb = x[(size_t)v * 16 + sub * 2 + 1];
            uint4 o;
            o.x = bpack(di * xa.x, di * xa.y);
            o.y = bpack(di * xa.z, di * xa.w);
            o.z = bpack(di * xb.x, di * xb.y);
            o.w = bpack(di * xb.z, di * xb.w);
            xs0[(size_t)v * 8 + sub] = o;
        }
    }
}

// --------------------- SpMM accumulation (shared body) ---------------------
// 32 lanes per node: 16 neighbors/iter (4 gather slots per lane), maskless
// full-group main loop with index prefetch distance 1, short tail. At the
// random-gather memory floor (R8: 410MB logical / 51us = 8TB/s L2+L3 mix).
#define SPMM_ACCUM_BODY                                                        \
    int half = threadIdx.x & 31;                                               \
    int nb = half >> 3, sub = half & 7;                                        \
    int beg = row_ptr[v];                                                      \
    int end = row_ptr[v + 1];                                                  \
    int full = (end - beg) >> 4;                                               \
    float a0 = 0, a1 = 0, a2 = 0, a3 = 0, a4 = 0, a5 = 0, a6 = 0, a7 = 0;      \
    int j = beg;                                                               \
    int s0 = 0, s1 = 0, s2 = 0, s3 = 0;                                        \
    if (full > 0) {                                                            \
        int b = j + 4 * nb;                                                    \
        s0 = csr_src[b];     s1 = csr_src[b + 1];                              \
        s2 = csr_src[b + 2]; s3 = csr_src[b + 3];                              \
    }                                                                          \
    for (int it = 0; it < full; ++it) {                                        \
        int jn = j + 16;                                                       \
        int t0 = 0, t1 = 0, t2 = 0, t3 = 0;                                    \
        if (it + 1 < full) {                                                   \
            int b = jn + 4 * nb;                                               \
            t0 = csr_src[b];     t1 = csr_src[b + 1];                          \
            t2 = csr_src[b + 2]; t3 = csr_src[b + 3];                          \
        }                                                                      \
        uint4 p0 = xs_in[(size_t)s0 * 8 + sub];                                \
        uint4 p1 = xs_in[(size_t)s1 * 8 + sub];                                \
        uint4 p2 = xs_in[(size_t)s2 * 8 + sub];                                \
        uint4 p3 = xs_in[(size_t)s3 * 8 + sub];                                \
        a0 += (blo(p0.x) + blo(p1.x)) + (blo(p2.x) + blo(p3.x));               \
        a1 += (bhi(p0.x) + bhi(p1.x)) + (bhi(p2.x) + bhi(p3.x));               \
        a2 += (blo(p0.y) + blo(p1.y)) + (blo(p2.y) + blo(p3.y));               \
        a3 += (bhi(p0.y) + bhi(p1.y)) + (bhi(p2.y) + bhi(p3.y));               \
        a4 += (blo(p0.z) + blo(p1.z)) + (blo(p2.z) + blo(p3.z));               \
        a5 += (bhi(p0.z) + bhi(p1.z)) + (bhi(p2.z) + bhi(p3.z));               \
        a6 += (blo(p0.w) + blo(p1.w)) + (blo(p2.w) + blo(p3.w));               \
        a7 += (bhi(p0.w) + bhi(p1.w)) + (bhi(p2.w) + bhi(p3.w));               \
        s0 = t0; s1 = t1; s2 = t2; s3 = t3;                                    \
        j = jn;                                                                \
    }                                                                          \
    for (int idx = j + nb; idx < end; idx += 4) {                              \
        int s = csr_src[idx];                                                  \
        uint4 p = xs_in[(size_t)s * 8 + sub];                                  \
        a0 += blo(p.x); a1 += bhi(p.x);                                        \
        a2 += blo(p.y); a3 += bhi(p.y);                                        \
        a4 += blo(p.z); a5 += bhi(p.z);                                        \
        a6 += blo(p.w); a7 += bhi(p.w);                                        \
    }                                                                          \
    a0 += __shfl_xor(a0, 8);  a0 += __shfl_xor(a0, 16);                        \
    a1 += __shfl_xor(a1, 8);  a1 += __shfl_xor(a1, 16);                        \
    a2 += __shfl_xor(a2, 8);  a2 += __shfl_xor(a2, 16);                        \
    a3 += __shfl_xor(a3, 8);  a3 += __shfl_xor(a3, 16);                        \
    a4 += __shfl_xor(a4, 8);  a4 += __shfl_xor(a4, 16);                        \
    a5 += __shfl_xor(a5, 8);  a5 += __shfl_xor(a5, 16);                        \
    a6 += __shfl_xor(a6, 8);  a6 += __shfl_xor(a6, 16);                        \
    a7 += __shfl_xor(a7, 8);  a7 += __shfl_xor(a7, 16);

// Layers 1,2: xs_out = bf16(dinv^2 * acc)
__global__ void spmm_bf16_kernel(const int* __restrict__ row_ptr,
                                 const int* __restrict__ csr_src,
                                 const float* __restrict__ dinv,
                                 const uint4* __restrict__ xs_in,
                                 uint4* __restrict__ xs_out, int N) {
    int t = blockIdx.x * blockDim.x + threadIdx.x;
    int v = t >> 5;
    if (v >= N) return;
    SPMM_ACCUM_BODY
    if (nb == 0) {
        float di = dinv[v];
        float d2 = di * di;
        uint4 o;
        o.x = bpack(d2 * a0, d2 * a1);
        o.y = bpack(d2 * a2, d2 * a3);
        o.z = bpack(d2 * a4, d2 * a5);
        o.w = bpack(d2 * a6, d2 * a7);
        xs_out[(size_t)v * 8 + sub] = o;
    }
}

// Layer 3 fused with final: out = 0.25*(x0 + rs*(xs1+xs2) + dinv*acc)
__global__ void spmm_last_kernel(const int* __restrict__ row_ptr,
                                 const int* __restrict__ csr_src,
                                 const float* __restrict__ dinv,
                                 const int* __restrict__ deg,
                                 const uint4* __restrict__ xs_in,   // xs2
                                 const uint4* __restrict__ xs1,
                                 const float4* __restrict__ x,
                                 float4* __restrict__ out, int N) {
    int t = blockIdx.x * blockDim.x + threadIdx.x;
    int v = t >> 5;
    if (v >= N) return;
    SPMM_ACCUM_BODY
    if (nb == 0) {
        float di = dinv[v];
        float rs = sqrtf((float)deg[v]);   // deg==0 -> 0, matches xs==0
        size_t idx = (size_t)v * 8 + sub;
        uint4 q1 = xs1[idx];
        uint4 q2 = xs_in[idx];
        float4 xa = x[(size_t)v * 16 + sub * 2];
        float4 xb = x[(size_t)v * 16 + sub * 2 + 1];
        float4 oa, ob;
        oa.x = 0.25f * (xa.x + rs * (blo(q1.x) + blo(q2.x)) + di * a0);
        oa.y = 0.25f * (xa.y + rs * (bhi(q1.x) + bhi(q2.x)) + di * a1);
        oa.z = 0.25f * (xa.z + rs * (blo(q1.y) + blo(q2.y)) + di * a2);
        oa.w = 0.25f * (xa.w + rs * (bhi(q1.y) + bhi(q2.y)) + di * a3);
        ob.x = 0.25f * (xb.x + rs * (blo(q1.z) + blo(q2.z)) + di * a4);
        ob.y = 0.25f * (xb.y + rs * (bhi(q1.z) + bhi(q2.z)) + di * a5);
        ob.z = 0.25f * (xb.z + rs * (blo(q1.w) + blo(q2.w)) + di * a6);
        ob.w = 0.25f * (xb.w + rs * (bhi(q1.w) + bhi(q2.w)) + di * a7);
        out[(size_t)v * 16 + sub * 2]     = oa;
        out[(size_t)v * 16 + sub * 2 + 1] = ob;
    }
}

extern "C" void kernel_launch(void* const* d_in, const int* in_sizes, int n_in,
                              void* d_out, int out_size, void* d_ws, size_t ws_size,
                              hipStream_t stream) {
    const float* x = (const float*)d_in[0];
    const int* adj = (const int*)d_in[1];
    float* out     = (float*)d_out;

    const int total_adj = in_sizes[1];   // 2*E entries in adj
    const int E = total_adj / 2;
    const int N = in_sizes[0] / DIM;
    const int NB = (N + BKT_G - 1) / BKT_G;   // dst buckets
    const int nhist = NB * NBLK;

    size_t BUF = (size_t)total_adj * 4;
    size_t xsb = (size_t)N * 32 * 4;
    if (xsb > BUF) BUF = xsb;
    BUF = (BUF + 255) & ~(size_t)255;

    char* ws = (char*)d_ws;
    int*      deg     = (int*)(ws);                               // 400KB
    float*    dinv    = (float*)(ws + (size_t)512 * 1024);        // 400KB
    int*      row_ptr = (int*)(ws + (size_t)1024 * 1024);         // 400KB+4
    int*      bsums   = (int*)(ws + (size_t)1536 * 1024);         // 1024 ints
    int*      hist    = (int*)(ws + (size_t)1600 * 1024);         // ~801KB
    int*      hist_s  = (int*)(ws + (size_t)2432 * 1024);         // ~801KB
    char*     big     = ws + (size_t)3264 * 1024;
    int*      csr_src = (int*)(big);
    unsigned* pairs   = (unsigned*)(big + BUF);     // dead after pass2
    uint4*    xs0     = (uint4*)(big + 2 * BUF);
    uint4*    xs1     = (uint4*)(big + 3 * BUF);
    uint4*    xs2     = (uint4*)(big + 4 * BUF);

    const int B = 256;

    // 1) per-(block,bucket) histogram — 4 LDS replicas, int4 loads
    hist_kernel<<<NBLK, HIST_B, NREP * NB * sizeof(int), stream>>>(adj, E, hist, NB);

    // 2) two-stage scan (scan_add fused into consumers; bucket base == bsums[g])
    const int nscan2 = (nhist + SCAN_B - 1) / SCAN_B;
    scan_block_kernel<<<nscan2, SCAN_B, 0, stream>>>(hist, nhist, hist_s, bsums);
    scan_sums_kernel<<<1, 1024, 0, stream>>>(bsums, nscan2);

    // 3) placement into bucket-grouped pairs (int4 loads, fused scan fix-up)
    place_kernel<<<NBLK, HIST_B, NB * sizeof(int), stream>>>(adj, E, hist_s,
                                                             bsums, pairs, NB);

    // 4) per-bucket: deg/dinv/row_ptr + csr scatter + fused xs0 init
    //    (single pairs read, records held in registers)
    pass2_build_kernel<<<NB, B, 0, stream>>>(pairs, bsums, (const float4*)x,
                                             csr_src, row_ptr, deg, dinv,
                                             xs0, N, NB, total_adj);

    // 5) layers 1,2 then fused layer3+final
    const int nblocks32 = (int)(((long long)N * 32 + B - 1) / B);
    spmm_bf16_kernel<<<nblocks32, B, 0, stream>>>(row_ptr, csr_src, dinv, xs0, xs1, N);
    spmm_bf16_kernel<<<nblocks32, B, 0, stream>>>(row_ptr, csr_src, dinv, xs1, xs2, N);
    spmm_last_kernel<<<nblocks32, B, 0, stream>>>(row_ptr, csr_src, dinv, deg,
                                                  xs2, xs1, (const float4*)x,
                                                  (float4*)out, N);
}